// Round 7
// baseline (194.056 us; speedup 1.0000x reference)
//
#include <hip/hip_runtime.h>
#include <float.h>

#define K_NN 10
#define BATCH 8
#define CIN 6
#define NPTS 4096
#define COUT 64
#define NSEG 8
#define SEGLEN (NPTS / NSEG)    // 512
#define CHUNK 8
#define NCHUNK (SEGLEN / CHUNK) // 64
#define CAP 20                  // survivor slots per (query,segment); cnt>=10 always
#define NEG_SLOPE 0.2f
#define BN_EPS 1e-5f

// ---- workspace layout (bytes) ----
// part[] (u16 x CAP) aliases q[]: consumed by merge before feat writes q.
// u16*20 == int*10 bytes -> SZ_Q identical to verified layout (10.49 MB).
static constexpr size_t OFF_IDX  = 0;                                                    // int[8*10*4096]
static constexpr size_t OFF_PTS  = OFF_IDX + (size_t)BATCH * K_NN * NPTS * sizeof(int);  // float4[8*4096]
static constexpr size_t OFF_PTSP = OFF_PTS + (size_t)BATCH * NPTS * sizeof(float4);      // float4[8*4096] pair-interleaved
static constexpr size_t OFF_Q    = OFF_PTSP + (size_t)BATCH * NPTS * sizeof(float4);     // alias: q / part
static constexpr size_t SZ_Q     = (size_t)NSEG * BATCH * NPTS * CAP * sizeof(unsigned short); // 10.49 MB
static constexpr size_t OFF_ST   = OFF_Q + SZ_Q;                                         // double[27]

typedef float v2f __attribute__((ext_vector_type(2)));

__device__ __forceinline__ float wave_sum(float v) {
#pragma unroll
    for (int m = 32; m >= 1; m >>= 1) v += __shfl_xor(v, m, 64);
    return v;
}
__device__ __forceinline__ float wave_max(float v) {
#pragma unroll
    for (int m = 32; m >= 1; m >>= 1) v = fmaxf(v, __shfl_xor(v, m, 64));
    return v;
}

// pts stores (2x, 2y, 2z, ||p||^2); query coords pre-halved once per thread.
// d' = 2*inner - ||c||^2 -> 3 FMAs. Monotone shift of true distance, used
// consistently everywhere. DO NOT reorder (bit-stable across rounds).
__device__ __forceinline__ float distp(float qx, float qy, float qz, float4 c) {
    return fmaf(c.x, qx, fmaf(c.y, qy, fmaf(c.z, qz, -c.w)));
}

// Packed pair distance: fa=(x0,x1,y0,y1), fb=(z0,z1,w0,w1) (pre-doubled xyz).
// __builtin_elementwise_fma == per-element fmaf -> BIT-IDENTICAL to distp for
// each point; lowers to v_pk_fma_f32 on gfx950 (packed fp32).
__device__ __forceinline__ v2f dist2(v2f qx2, v2f qy2, v2f qz2, float4 fa, float4 fb) {
    v2f cx = {fa.x, fa.y}, cy = {fa.z, fa.w}, cz = {fb.x, fb.y}, cw = {fb.z, fb.w};
#if __has_builtin(__builtin_elementwise_fma)
    v2f t = __builtin_elementwise_fma(cz, qz2, -cw);
    t = __builtin_elementwise_fma(cy, qy2, t);
    t = __builtin_elementwise_fma(cx, qx2, t);
    return t;
#else
    v2f t;
    t[0] = fmaf(cx[0], qx2[0], fmaf(cy[0], qy2[0], fmaf(cz[0], qz2[0], -cw[0])));
    t[1] = fmaf(cx[1], qx2[1], fmaf(cy[1], qy2[1], fmaf(cz[1], qz2[1], -cw[1])));
    return t;
#endif
}

__device__ __forceinline__ float fmax3(float a, float b, float c) {
    return fmaxf(fmaxf(a, b), c);   // fuses to v_max3_f32 (exact for non-NaN)
}

// 10-deep chunk-max chain level
#define CHL(cj) { float _hi = fmaxf(cj, t); t = fminf(cj, t); cj = _hi; }

// one conditional swap level of the insertion sort
#define CSWP(va, vb, ia, ib) \
    if (va > vb) { float _tv = va; va = vb; vb = _tv; int _ti = ia; ia = ib; ib = _ti; }

// exact strict-> insertion of (d,m) into descending list v0..v9 / i0..i9
#define INSERT10(dd, mm) \
    if ((dd) > v9) { \
        v9 = (dd); i9 = (mm); \
        CSWP(v9, v8, i9, i8) \
        CSWP(v8, v7, i8, i7) \
        CSWP(v7, v6, i7, i6) \
        CSWP(v6, v5, i6, i5) \
        CSWP(v5, v4, i5, i4) \
        CSWP(v4, v3, i4, i3) \
        CSWP(v3, v2, i3, i2) \
        CSWP(v2, v1, i2, i1) \
        CSWP(v1, v0, i1, i0) \
    }

// ---- Kernel P: pack pts + pair-interleaved ptsp; block 0 zeroes stats ----
__global__ __launch_bounds__(256) void prep_pts(const float* __restrict__ x,
                                                float4* __restrict__ pts,
                                                float4* __restrict__ ptsp,
                                                double* __restrict__ stats) {
    if (blockIdx.x == 0 && threadIdx.x < 27) stats[threadIdx.x] = 0.0;
    int t = blockIdx.x * 256 + threadIdx.x;   // 0..32767
    int b = t >> 12;
    int n = t & (NPTS - 1);
    const float* xb = x + (size_t)b * CIN * NPTS;
    float X = xb[n];
    float Y = xb[NPTS + n];
    float Z = xb[2 * NPTS + n];
    float w = X * X + Y * Y + Z * Z;
    pts[t] = make_float4(2.0f * X, 2.0f * Y, 2.0f * Z, w);
    // neighbor (n+1) via shuffle; even lanes write the pair record
    float Xn = __shfl_down(X, 1, 64);
    float Yn = __shfl_down(Y, 1, 64);
    float Zn = __shfl_down(Z, 1, 64);
    float wn = __shfl_down(w, 1, 64);
    if ((n & 1) == 0) {
        float4* pb = ptsp + (size_t)b * NPTS;
        pb[n]     = make_float4(2.0f * X, 2.0f * Xn, 2.0f * Y, 2.0f * Yn);
        pb[n + 1] = make_float4(2.0f * Z, 2.0f * Zn, w, wn);
    }
}

// ---- Kernel A1: per-segment survivor-set (supersedes exact per-seg top-10) ----
// Phase 1: chunk maxima (CHUNK=8, packed distances) through 10-deep chain ->
//          thr = 10th-largest of 64 chunk maxima (>=10 distinct chunks each
//          hold >=1 elem >= thr => thr <= exact v10).
// Phase 2: DIRECT-STORE survivors (d >= thr) to part (u16, CAP=20 slots),
//          ascending index; pad sentinels 0xFFFF. No drain, no INSERT in knn.
//          Correct: S = {d>=thr} contains the segment's contribution to the
//          global top-10; merge re-evaluates distances anyway. cnt>=10 always.
// Fallback (cnt>CAP, rare): exec-masked exact rescan writes true top-10.
__global__ __launch_bounds__(256, 4) void knn_part(const float4* __restrict__ pts,
                                                   const float4* __restrict__ ptsp,
                                                   unsigned short* __restrict__ part) {
    int b = blockIdx.y;
    int s = blockIdx.z;
    int n = blockIdx.x * 256 + threadIdx.x;
    const float4* p  = pts  + (size_t)b * NPTS;   // wave-uniform base -> scalar loads
    const float4* p2 = ptsp + (size_t)b * NPTS;
    float4 q4 = p[n];
    float qx = 0.5f * q4.x, qy = 0.5f * q4.y, qz = 0.5f * q4.z;
    v2f qx2 = {qx, qx}, qy2 = {qy, qy}, qz2 = {qz, qz};
    int m0 = s * SEGLEN;

    // ---- phase 1: threshold from 64 chunk maxima (8 pts = 4 pairs each) ----
    float c0 = -FLT_MAX, c1 = -FLT_MAX, c2 = -FLT_MAX, c3 = -FLT_MAX, c4 = -FLT_MAX;
    float c5 = -FLT_MAX, c6 = -FLT_MAX, c7 = -FLT_MAX, c8 = -FLT_MAX, c9 = -FLT_MAX;

    for (int ch = 0; ch < NCHUNK; ch++) {
        const float4* cp = p2 + (m0 + ch * CHUNK);   // 8 float4 = 4 pairs
        v2f e0 = dist2(qx2, qy2, qz2, cp[0], cp[1]);
        v2f e1 = dist2(qx2, qy2, qz2, cp[2], cp[3]);
        v2f e2 = dist2(qx2, qy2, qz2, cp[4], cp[5]);
        v2f e3 = dist2(qx2, qy2, qz2, cp[6], cp[7]);
        float a0 = fmax3(e0[0], e0[1], e1[0]);
        float a1 = fmax3(e1[1], e2[0], e2[1]);
        float a2 = fmax3(e3[0], e3[1], a0);
        float t = fmaxf(a1, a2);
        CHL(c0) CHL(c1) CHL(c2) CHL(c3) CHL(c4)
        CHL(c5) CHL(c6) CHL(c7) CHL(c8) CHL(c9)
    }
    float thr = c9;   // 10th-largest chunk max (<= exact v10)

    // ---- phase 2: direct-store survivors (ascending index) ----
    unsigned short* o = part + (((size_t)s * BATCH + b) * CAP) * NPTS + n;
    int cnt = 0;
    for (int pr = 0; pr < SEGLEN / 2; pr++) {
        v2f d2 = dist2(qx2, qy2, qz2, p2[m0 + 2 * pr], p2[m0 + 2 * pr + 1]);
        int m = m0 + 2 * pr;
        if (d2[0] >= thr) { o[(size_t)min(cnt, CAP - 1) * NPTS] = (unsigned short)m;       cnt++; }
        if (d2[1] >= thr) { o[(size_t)min(cnt, CAP - 1) * NPTS] = (unsigned short)(m + 1); cnt++; }
    }
    for (int j = cnt; j < CAP; j++) o[(size_t)j * NPTS] = 0xFFFFu;

    // ---- fallback: exact top-10 for overflow lanes (rare, exec-masked) ----
    if (cnt > CAP) {
        float v0 = -FLT_MAX, v1 = -FLT_MAX, v2 = -FLT_MAX, v3 = -FLT_MAX, v4 = -FLT_MAX;
        float v5 = -FLT_MAX, v6 = -FLT_MAX, v7 = -FLT_MAX, v8 = -FLT_MAX, v9 = -FLT_MAX;
        int i0 = 0, i1 = 0, i2 = 0, i3 = 0, i4 = 0;
        int i5 = 0, i6 = 0, i7 = 0, i8 = 0, i9 = 0;
        for (int mm = 0; mm < SEGLEN; mm++) {
            int m = m0 + mm;
            float d = distp(qx, qy, qz, p[m]);
            INSERT10(d, m)
        }
        o[(size_t)0 * NPTS] = (unsigned short)i0;
        o[(size_t)1 * NPTS] = (unsigned short)i1;
        o[(size_t)2 * NPTS] = (unsigned short)i2;
        o[(size_t)3 * NPTS] = (unsigned short)i3;
        o[(size_t)4 * NPTS] = (unsigned short)i4;
        o[(size_t)5 * NPTS] = (unsigned short)i5;
        o[(size_t)6 * NPTS] = (unsigned short)i6;
        o[(size_t)7 * NPTS] = (unsigned short)i7;
        o[(size_t)8 * NPTS] = (unsigned short)i8;
        o[(size_t)9 * NPTS] = (unsigned short)i9;
        for (int j = K_NN; j < CAP; j++) o[(size_t)j * NPTS] = 0xFFFFu;
    }
}

// ---- Kernel A2: merge survivor lists -> global top-10, 4-wave cooperative ----
// Wave w scans segments {2w,2w+1} (2x20 slots, sentinel-skip), publishes its
// top-10 via LDS; wave 0 merges 4x10. Candidate order = globally ascending
// point index -> strict-> insertion keeps lowest index on ties (== top_k).
__global__ __launch_bounds__(256, 8) void merge_kernel(const float4* __restrict__ pts,
                                                       const unsigned short* __restrict__ part,
                                                       int* __restrict__ idxo) {
    __shared__ float dml[4][K_NN][64];
    __shared__ unsigned short iml[4][K_NN][64];

    int b  = blockIdx.y;
    int ln = threadIdx.x & 63;
    int wv = threadIdx.x >> 6;
    int wvu = __builtin_amdgcn_readfirstlane(wv);   // uniform (round-2 lesson)
    int n  = blockIdx.x * 64 + ln;
    const float4* p = pts + (size_t)b * NPTS;
    float4 q4 = p[n];
    float qx = 0.5f * q4.x, qy = 0.5f * q4.y, qz = 0.5f * q4.z;

    float v0 = -FLT_MAX, v1 = -FLT_MAX, v2 = -FLT_MAX, v3 = -FLT_MAX, v4 = -FLT_MAX;
    float v5 = -FLT_MAX, v6 = -FLT_MAX, v7 = -FLT_MAX, v8 = -FLT_MAX, v9 = -FLT_MAX;
    int i0 = 0, i1 = 0, i2 = 0, i3 = 0, i4 = 0;
    int i5 = 0, i6 = 0, i7 = 0, i8 = 0, i9 = 0;

#pragma unroll
    for (int t = 0; t < 2; t++) {
        int s = 2 * wvu + t;                     // uniform segment id
        const unsigned short* pp = part + (((size_t)s * BATCH + b) * CAP) * NPTS + n;
#pragma unroll 4
        for (int j = 0; j < CAP; j++) {
            int m = pp[(size_t)j * NPTS];
            if (m == 0xFFFF) continue;           // sentinel pad
            float4 cc = p[m];                    // divergent but L1/L2-resident
            float d = distp(qx, qy, qz, cc);
            INSERT10(d, m)
        }
    }

    dml[wv][0][ln] = v0; iml[wv][0][ln] = (unsigned short)i0;
    dml[wv][1][ln] = v1; iml[wv][1][ln] = (unsigned short)i1;
    dml[wv][2][ln] = v2; iml[wv][2][ln] = (unsigned short)i2;
    dml[wv][3][ln] = v3; iml[wv][3][ln] = (unsigned short)i3;
    dml[wv][4][ln] = v4; iml[wv][4][ln] = (unsigned short)i4;
    dml[wv][5][ln] = v5; iml[wv][5][ln] = (unsigned short)i5;
    dml[wv][6][ln] = v6; iml[wv][6][ln] = (unsigned short)i6;
    dml[wv][7][ln] = v7; iml[wv][7][ln] = (unsigned short)i7;
    dml[wv][8][ln] = v8; iml[wv][8][ln] = (unsigned short)i8;
    dml[wv][9][ln] = v9; iml[wv][9][ln] = (unsigned short)i9;
    __syncthreads();

    if (wvu == 0) {
        float v0 = -FLT_MAX, v1 = -FLT_MAX, v2 = -FLT_MAX, v3 = -FLT_MAX, v4 = -FLT_MAX;
        float v5 = -FLT_MAX, v6 = -FLT_MAX, v7 = -FLT_MAX, v8 = -FLT_MAX, v9 = -FLT_MAX;
        int i0 = 0, i1 = 0, i2 = 0, i3 = 0, i4 = 0;
        int i5 = 0, i6 = 0, i7 = 0, i8 = 0, i9 = 0;
#pragma unroll
        for (int w = 0; w < 4; w++) {
#pragma unroll
            for (int j = 0; j < K_NN; j++) {
                float d = dml[w][j][ln];
                int m = iml[w][j][ln];
                INSERT10(d, m)
            }
        }
        int* o = idxo + (size_t)b * K_NN * NPTS + n;
        o[(size_t)0 * NPTS] = i0;
        o[(size_t)1 * NPTS] = i1;
        o[(size_t)2 * NPTS] = i2;
        o[(size_t)3 * NPTS] = i3;
        o[(size_t)4 * NPTS] = i4;
        o[(size_t)5 * NPTS] = i5;
        o[(size_t)6 * NPTS] = i6;
        o[(size_t)7 * NPTS] = i7;
        o[(size_t)8 * NPTS] = i8;
        o[(size_t)9 * NPTS] = i9;
    }
}

// ---- Kernel B: gather + center + q[b,o,n] = max_k (W feat) + moment stats ----
// grid.z = 4 output-groups (16 outputs each); stats only in z==0 blocks.
__global__ __launch_bounds__(256) void feat_kernel(const float4* __restrict__ pts,
                                                   const float* __restrict__ x,
                                                   const float* __restrict__ W,
                                                   const int* __restrict__ idx,
                                                   float* __restrict__ q,
                                                   double* __restrict__ stats) {
    __shared__ float sW[COUT * CIN];
    __shared__ float sred[4][27];
    for (int i = threadIdx.x; i < COUT * CIN; i += 256) sW[i] = W[i];
    __syncthreads();

    int b = blockIdx.y;
    int og = blockIdx.z;           // output group: o in [16*og, 16*og+16)
    int n = blockIdx.x * 256 + threadIdx.x;
    const float* xb = x + (size_t)b * CIN * NPTS;
    const float4* p = pts + (size_t)b * NPTS;

    int nb[K_NN];
#pragma unroll
    for (int k = 0; k < K_NN; k++) nb[k] = idx[((size_t)b * K_NN + k) * NPTS + n];

    float f[CIN][K_NN];
#pragma unroll
    for (int k = 0; k < K_NN; k++) {
        float4 c = p[nb[k]];                    // xyz in one 16B gather (doubled)
        f[0][k] = 0.5f * c.x; f[1][k] = 0.5f * c.y; f[2][k] = 0.5f * c.z;
    }
#pragma unroll
    for (int c = 3; c < CIN; c++)
#pragma unroll
        for (int k = 0; k < K_NN; k++)
            f[c][k] = xb[c * NPTS + nb[k]];

    // center xyz over k, scale by 10
#pragma unroll
    for (int c = 0; c < 3; c++) {
        float s = 0.f;
#pragma unroll
        for (int k = 0; k < K_NN; k++) s += f[c][k];
        float m = s / 10.0f;
#pragma unroll
        for (int k = 0; k < K_NN; k++) f[c][k] = (f[c][k] - m) * 10.0f;
    }

    // q[b,o,n] = max_k y for this block's 16 outputs (same per-o op order)
    float* qb = q + (size_t)b * COUT * NPTS + n;
    int o0 = og * 16;
#pragma unroll
    for (int oo = 0; oo < 16; oo++) {
        int o = o0 + oo;
        float w0 = sW[o * 6 + 0], w1 = sW[o * 6 + 1], w2 = sW[o * 6 + 2];
        float w3 = sW[o * 6 + 3], w4 = sW[o * 6 + 4], w5 = sW[o * 6 + 5];
        float mx = -FLT_MAX;
#pragma unroll
        for (int k = 0; k < K_NN; k++) {
            float y = w0 * f[0][k] + w1 * f[1][k] + w2 * f[2][k] +
                      w3 * f[3][k] + w4 * f[4][k] + w5 * f[5][k];
            mx = fmaxf(mx, y);
        }
        qb[(size_t)o * NPTS] = mx;
    }

    if (og != 0) return;   // stats once (block-uniform branch; sync below safe)

    // moment stats: S1[6], S2[21]
    float s1[CIN];
#pragma unroll
    for (int c = 0; c < CIN; c++) {
        float s = 0.f;
#pragma unroll
        for (int k = 0; k < K_NN; k++) s += f[c][k];
        s1[c] = s;
    }
    float s2[21];
#pragma unroll
    for (int i = 0; i < 21; i++) s2[i] = 0.f;
#pragma unroll
    for (int k = 0; k < K_NN; k++) {
        int pp = 0;
#pragma unroll
        for (int c = 0; c < CIN; c++)
#pragma unroll
            for (int c2 = c; c2 < CIN; c2++) {
                s2[pp] += f[c][k] * f[c2][k];
                pp++;
            }
    }
#pragma unroll
    for (int c = 0; c < CIN; c++) s1[c] = wave_sum(s1[c]);
#pragma unroll
    for (int i = 0; i < 21; i++) s2[i] = wave_sum(s2[i]);

    int wv = threadIdx.x >> 6;
    int ln = threadIdx.x & 63;
    if (ln == 0) {
#pragma unroll
        for (int c = 0; c < CIN; c++) sred[wv][c] = s1[c];
#pragma unroll
        for (int i = 0; i < 21; i++) sred[wv][6 + i] = s2[i];
    }
    __syncthreads();
    if (threadIdx.x < 27) {
        float t = sred[0][threadIdx.x] + sred[1][threadIdx.x] +
                  sred[2][threadIdx.x] + sred[3][threadIdx.x];
        atomicAdd(&stats[threadIdx.x], (double)t);
    }
}

// ---- Kernel C: fold moments -> scale/shift (in-block); leaky; reduce max+mean ----
__global__ __launch_bounds__(256) void reduce_kernel(const float* __restrict__ q,
                                                     const double* __restrict__ stats,
                                                     const float* __restrict__ W,
                                                     const float* __restrict__ gamma,
                                                     const float* __restrict__ beta,
                                                     float* __restrict__ out) {
    int o = blockIdx.x;
    int b = blockIdx.y;

    __shared__ float s_sc, s_sh;
    if (threadIdx.x == 0) {
        const double minv = 1.0 / (double)((size_t)BATCH * NPTS * K_NN);
        double w[CIN];
#pragma unroll
        for (int c = 0; c < CIN; c++) w[c] = (double)W[o * CIN + c];
        double mu = 0.0;
#pragma unroll
        for (int c = 0; c < CIN; c++) mu += w[c] * stats[c];
        mu *= minv;
        double ey2 = 0.0;
        int pp = 6;
#pragma unroll
        for (int c = 0; c < CIN; c++)
#pragma unroll
            for (int c2 = c; c2 < CIN; c2++) {
                double v = w[c] * w[c2] * stats[pp];
                ey2 += (c2 == c) ? v : 2.0 * v;
                pp++;
            }
        ey2 *= minv;
        double var = ey2 - mu * mu;
        float scale = gamma[o] * rsqrtf((float)var + BN_EPS);
        float shift = beta[o] - (float)mu * scale;
        s_sc = scale;
        s_sh = shift;
    }
    __syncthreads();
    float scale = s_sc, shift = s_sh;

    const float* qp = q + ((size_t)b * COUT + o) * NPTS;
    float mx = -FLT_MAX, sm = 0.f;
    for (int i = threadIdx.x; i < NPTS; i += 256) {
        float z = scale * qp[i] + shift;
        z = (z >= 0.f) ? z : NEG_SLOPE * z;
        mx = fmaxf(mx, z);
        sm += z;
    }
    mx = wave_max(mx);
    sm = wave_sum(sm);
    __shared__ float smx[4], ssm2[4];
    int wv = threadIdx.x >> 6;
    int ln = threadIdx.x & 63;
    if (ln == 0) { smx[wv] = mx; ssm2[wv] = sm; }
    __syncthreads();
    if (threadIdx.x == 0) {
        float m = fmaxf(fmaxf(smx[0], smx[1]), fmaxf(smx[2], smx[3]));
        float s = ssm2[0] + ssm2[1] + ssm2[2] + ssm2[3];
        out[b * 2 * COUT + o] = m;
        out[b * 2 * COUT + COUT + o] = s * (1.0f / (float)NPTS);
    }
}

extern "C" void kernel_launch(void* const* d_in, const int* in_sizes, int n_in,
                              void* d_out, int out_size, void* d_ws, size_t ws_size,
                              hipStream_t stream) {
    const float* x     = (const float*)d_in[0];
    const float* W     = (const float*)d_in[1];
    const float* gamma = (const float*)d_in[2];
    const float* beta  = (const float*)d_in[3];
    float* out = (float*)d_out;

    char* ws = (char*)d_ws;
    int*    idx   = (int*)(ws + OFF_IDX);
    float4* pts   = (float4*)(ws + OFF_PTS);
    float4* ptsp  = (float4*)(ws + OFF_PTSP);
    unsigned short* part = (unsigned short*)(ws + OFF_Q); // aliases q (consumed first)
    float*  q     = (float*)(ws + OFF_Q);
    double* stats = (double*)(ws + OFF_ST);

    prep_pts<<<BATCH * NPTS / 256, 256, 0, stream>>>(x, pts, ptsp, stats);
    knn_part<<<dim3(NPTS / 256, BATCH, NSEG), 256, 0, stream>>>(pts, ptsp, part);
    merge_kernel<<<dim3(NPTS / 64, BATCH), 256, 0, stream>>>(pts, part, idx);
    feat_kernel<<<dim3(NPTS / 256, BATCH, 4), 256, 0, stream>>>(pts, x, W, idx, q, stats);
    reduce_kernel<<<dim3(COUT, BATCH), 256, 0, stream>>>(q, stats, W, gamma, beta, out);
}

// Round 8
// 182.506 us; speedup vs baseline: 1.0633x; 1.0633x over previous
//
#include <hip/hip_runtime.h>
#include <float.h>

#define K_NN 10
#define BATCH 8
#define CIN 6
#define NPTS 4096
#define COUT 64
#define NSEG 8
#define SEGLEN (NPTS / NSEG)    // 512
#define CHUNK 16
#define NCHUNK (SEGLEN / CHUNK) // 32
#define NWORD (SEGLEN / 32)     // 16
#define NEG_SLOPE 0.2f
#define BN_EPS 1e-5f

// ---- workspace layout (bytes) ----
// part[] aliases q[]: part is fully consumed by merge_kernel before feat_kernel writes q.
static constexpr size_t OFF_IDX  = 0;                                                    // int[8*10*4096]
static constexpr size_t OFF_PTS  = OFF_IDX + (size_t)BATCH * K_NN * NPTS * sizeof(int);  // float4[8*4096] (2x,2y,2z,|p|^2)
static constexpr size_t OFF_PTS2 = OFF_PTS + (size_t)BATCH * NPTS * sizeof(float4);      // float4[8*4096] (x3,x4,x5,0)
static constexpr size_t OFF_Q    = OFF_PTS2 + (size_t)BATCH * NPTS * sizeof(float4);     // alias: q / part
static constexpr size_t SZ_Q     = (size_t)NSEG * BATCH * NPTS * K_NN * sizeof(int);     // 10.49 MB
static constexpr size_t OFF_ST   = OFF_Q + SZ_Q;                                         // double[27]

__device__ __forceinline__ float wave_sum(float v) {
#pragma unroll
    for (int m = 32; m >= 1; m >>= 1) v += __shfl_xor(v, m, 64);
    return v;
}
__device__ __forceinline__ float wave_max(float v) {
#pragma unroll
    for (int m = 32; m >= 1; m >>= 1) v = fmaxf(v, __shfl_xor(v, m, 64));
    return v;
}

// pts stores (2x, 2y, 2z, ||p||^2); query coords pre-halved once per thread.
// d' = 2*inner - ||c||^2 -> 3 FMAs. Monotone shift of true distance, used
// consistently in knn_part/drain/merge. DO NOT reorder (bit-stable).
__device__ __forceinline__ float distp(float qx, float qy, float qz, float4 c) {
    return fmaf(c.x, qx, fmaf(c.y, qy, fmaf(c.z, qz, -c.w)));
}

__device__ __forceinline__ float fmax3(float a, float b, float c) {
    return fmaxf(fmaxf(a, b), c);   // fuses to v_max3_f32 (exact for non-NaN)
}

// 10-deep chunk-max chain level
#define CHL(cj) { float _hi = fmaxf(cj, t); t = fminf(cj, t); cj = _hi; }

// one conditional swap level of the insertion sort
#define CSWP(va, vb, ia, ib) \
    if (va > vb) { float _tv = va; va = vb; vb = _tv; int _ti = ia; ia = ib; ib = _ti; }

// exact strict-> insertion of (d,m) into descending list v0..v9 / i0..i9
#define INSERT10(dd, mm) \
    if ((dd) > v9) { \
        v9 = (dd); i9 = (mm); \
        CSWP(v9, v8, i9, i8) \
        CSWP(v8, v7, i8, i7) \
        CSWP(v7, v6, i7, i6) \
        CSWP(v6, v5, i6, i5) \
        CSWP(v5, v4, i5, i4) \
        CSWP(v4, v3, i4, i3) \
        CSWP(v3, v2, i3, i2) \
        CSWP(v2, v1, i2, i1) \
        CSWP(v1, v0, i1, i0) \
    }

// ---- Kernel P: pack pts (2x,2y,2z,|p|^2) + pts2 (x3,x4,x5); zero stats ----
__global__ __launch_bounds__(256) void prep_pts(const float* __restrict__ x,
                                                float4* __restrict__ pts,
                                                float4* __restrict__ pts2,
                                                double* __restrict__ stats) {
    if (blockIdx.x == 0 && threadIdx.x < 27) stats[threadIdx.x] = 0.0;
    int t = blockIdx.x * 256 + threadIdx.x;   // 0..32767
    int b = t >> 12;
    int n = t & (NPTS - 1);
    const float* xb = x + (size_t)b * CIN * NPTS;
    float x0 = xb[n];
    float x1 = xb[NPTS + n];
    float x2 = xb[2 * NPTS + n];
    pts[t] = make_float4(2.0f * x0, 2.0f * x1, 2.0f * x2, x0 * x0 + x1 * x1 + x2 * x2);
    float x3 = xb[3 * NPTS + n];
    float x4 = xb[4 * NPTS + n];
    float x5 = xb[5 * NPTS + n];
    pts2[t] = make_float4(x3, x4, x5, 0.0f);
}

// ---- Kernel A1: per-segment exact top-10 (FROZEN round-6 configuration) ----
// Measured floor ~78 us across 6 structural variants (rounds 1-7): not VALU-
// issue (r7: -26% insts, same time), not occupancy (r3/r5), not registers
// (r4). Constant = two scalar-load passes over candidates. DO NOT RESTRUCTURE.
__global__ __launch_bounds__(256, 4) void knn_part(const float4* __restrict__ pts,
                                                   int* __restrict__ part) {
    int b = blockIdx.y;
    int s = blockIdx.z;
    int n = blockIdx.x * 256 + threadIdx.x;
    const float4* p = pts + (size_t)b * NPTS;   // wave-uniform base -> scalar loads
    float4 q4 = p[n];
    float qx = 0.5f * q4.x, qy = 0.5f * q4.y, qz = 0.5f * q4.z;
    int m0 = s * SEGLEN;

    // ---- phase 1: threshold from chunk maxima ----
    float c0 = -FLT_MAX, c1 = -FLT_MAX, c2 = -FLT_MAX, c3 = -FLT_MAX, c4 = -FLT_MAX;
    float c5 = -FLT_MAX, c6 = -FLT_MAX, c7 = -FLT_MAX, c8 = -FLT_MAX, c9 = -FLT_MAX;

    for (int ch = 0; ch < NCHUNK; ch++) {
        const float4* cp = p + (m0 + ch * CHUNK);
        float d0  = distp(qx, qy, qz, cp[0]);
        float d1  = distp(qx, qy, qz, cp[1]);
        float d2  = distp(qx, qy, qz, cp[2]);
        float d3  = distp(qx, qy, qz, cp[3]);
        float d4  = distp(qx, qy, qz, cp[4]);
        float d5  = distp(qx, qy, qz, cp[5]);
        float d6  = distp(qx, qy, qz, cp[6]);
        float d7  = distp(qx, qy, qz, cp[7]);
        float d8  = distp(qx, qy, qz, cp[8]);
        float d9  = distp(qx, qy, qz, cp[9]);
        float d10 = distp(qx, qy, qz, cp[10]);
        float d11 = distp(qx, qy, qz, cp[11]);
        float d12 = distp(qx, qy, qz, cp[12]);
        float d13 = distp(qx, qy, qz, cp[13]);
        float d14 = distp(qx, qy, qz, cp[14]);
        float d15 = distp(qx, qy, qz, cp[15]);
        float a0 = fmax3(d0, d1, d2);
        float a1 = fmax3(d3, d4, d5);
        float a2 = fmax3(d6, d7, d8);
        float a3 = fmax3(d9, d10, d11);
        float a4 = fmax3(d12, d13, d14);
        float t = fmaxf(fmax3(fmax3(a0, a1, a2), a3, a4), d15);
        CHL(c0) CHL(c1) CHL(c2) CHL(c3) CHL(c4)
        CHL(c5) CHL(c6) CHL(c7) CHL(c8) CHL(c9)
    }
    float thr = c9;   // 10th-largest chunk max (<= exact v10)

    // ---- phase 2 + drain: bitmask survivors, exact strict-> insert ----
    float v0 = -FLT_MAX, v1 = -FLT_MAX, v2 = -FLT_MAX, v3 = -FLT_MAX, v4 = -FLT_MAX;
    float v5 = -FLT_MAX, v6 = -FLT_MAX, v7 = -FLT_MAX, v8 = -FLT_MAX, v9 = -FLT_MAX;
    int i0 = 0, i1 = 0, i2 = 0, i3 = 0, i4 = 0;
    int i5 = 0, i6 = 0, i7 = 0, i8 = 0, i9 = 0;

    for (int w = 0; w < NWORD; w++) {
        const float4* cp = p + (m0 + w * 32);
        unsigned int mask = 0u;
#pragma unroll
        for (int u = 0; u < 32; u++) {
            float d = distp(qx, qy, qz, cp[u]);
            mask = (mask << 1) | (d >= thr ? 1u : 0u);   // point u -> bit (31-u)
        }
        int base = m0 + w * 32;
        while (mask) {
            int j = __builtin_clz(mask);        // MSB-first == ascending m
            mask ^= (0x80000000u >> j);
            int m = base + j;
            float4 cc = p[m];                   // divergent, L1-hot (segment = 8 KB)
            float d = distp(qx, qy, qz, cc);
            INSERT10(d, m)
        }
    }

    int* o = part + (((size_t)s * BATCH + b) * K_NN) * NPTS + n;
    o[(size_t)0 * NPTS] = i0;
    o[(size_t)1 * NPTS] = i1;
    o[(size_t)2 * NPTS] = i2;
    o[(size_t)3 * NPTS] = i3;
    o[(size_t)4 * NPTS] = i4;
    o[(size_t)5 * NPTS] = i5;
    o[(size_t)6 * NPTS] = i6;
    o[(size_t)7 * NPTS] = i7;
    o[(size_t)8 * NPTS] = i8;
    o[(size_t)9 * NPTS] = i9;
}

// ---- Kernel A2: merge 8 segment lists -> global top-10, 8-wave cooperative ----
// ROUND-8: wave w owns segment w alone (10 cands; serial divergent-gather
// chain halved vs r6's 20), 512-thread blocks, 4096 waves (4/SIMD). Wave 0
// merges 8x10 in (s asc, j asc) == ascending candidate order -> identical tie
// semantics to a flat ascending scan (prefix property, proven r3/r6).
__global__ __launch_bounds__(512, 8) void merge_kernel(const float4* __restrict__ pts,
                                                       const int* __restrict__ part,
                                                       int* __restrict__ idxo) {
    __shared__ float dml[NSEG][K_NN][64];
    __shared__ unsigned short iml[NSEG][K_NN][64];

    int b  = blockIdx.y;
    int ln = threadIdx.x & 63;
    int wv = threadIdx.x >> 6;
    int wvu = __builtin_amdgcn_readfirstlane(wv);   // uniform (round-2 lesson)
    int n  = blockIdx.x * 64 + ln;
    const float4* p = pts + (size_t)b * NPTS;
    float4 q4 = p[n];
    float qx = 0.5f * q4.x, qy = 0.5f * q4.y, qz = 0.5f * q4.z;

    float v0 = -FLT_MAX, v1 = -FLT_MAX, v2 = -FLT_MAX, v3 = -FLT_MAX, v4 = -FLT_MAX;
    float v5 = -FLT_MAX, v6 = -FLT_MAX, v7 = -FLT_MAX, v8 = -FLT_MAX, v9 = -FLT_MAX;
    int i0 = 0, i1 = 0, i2 = 0, i3 = 0, i4 = 0;
    int i5 = 0, i6 = 0, i7 = 0, i8 = 0, i9 = 0;

    {
        const int* pp = part + (((size_t)wvu * BATCH + b) * K_NN) * NPTS + n;
#pragma unroll
        for (int j = 0; j < K_NN; j++) {
            int m = pp[(size_t)j * NPTS];
            float4 cc = p[m];                    // divergent but L1/L2-resident
            float d = distp(qx, qy, qz, cc);
            INSERT10(d, m)
        }
    }

    dml[wv][0][ln] = v0; iml[wv][0][ln] = (unsigned short)i0;
    dml[wv][1][ln] = v1; iml[wv][1][ln] = (unsigned short)i1;
    dml[wv][2][ln] = v2; iml[wv][2][ln] = (unsigned short)i2;
    dml[wv][3][ln] = v3; iml[wv][3][ln] = (unsigned short)i3;
    dml[wv][4][ln] = v4; iml[wv][4][ln] = (unsigned short)i4;
    dml[wv][5][ln] = v5; iml[wv][5][ln] = (unsigned short)i5;
    dml[wv][6][ln] = v6; iml[wv][6][ln] = (unsigned short)i6;
    dml[wv][7][ln] = v7; iml[wv][7][ln] = (unsigned short)i7;
    dml[wv][8][ln] = v8; iml[wv][8][ln] = (unsigned short)i8;
    dml[wv][9][ln] = v9; iml[wv][9][ln] = (unsigned short)i9;
    __syncthreads();

    if (wvu == 0) {
        float v0 = -FLT_MAX, v1 = -FLT_MAX, v2 = -FLT_MAX, v3 = -FLT_MAX, v4 = -FLT_MAX;
        float v5 = -FLT_MAX, v6 = -FLT_MAX, v7 = -FLT_MAX, v8 = -FLT_MAX, v9 = -FLT_MAX;
        int i0 = 0, i1 = 0, i2 = 0, i3 = 0, i4 = 0;
        int i5 = 0, i6 = 0, i7 = 0, i8 = 0, i9 = 0;
#pragma unroll
        for (int w = 0; w < NSEG; w++) {
#pragma unroll
            for (int j = 0; j < K_NN; j++) {
                float d = dml[w][j][ln];
                int m = iml[w][j][ln];
                INSERT10(d, m)
            }
        }
        int* o = idxo + (size_t)b * K_NN * NPTS + n;
        o[(size_t)0 * NPTS] = i0;
        o[(size_t)1 * NPTS] = i1;
        o[(size_t)2 * NPTS] = i2;
        o[(size_t)3 * NPTS] = i3;
        o[(size_t)4 * NPTS] = i4;
        o[(size_t)5 * NPTS] = i5;
        o[(size_t)6 * NPTS] = i6;
        o[(size_t)7 * NPTS] = i7;
        o[(size_t)8 * NPTS] = i8;
        o[(size_t)9 * NPTS] = i9;
    }
}

// ---- Kernel B: gather + center + q[b,o,n] = max_k (W feat) + moment stats ----
// grid.z = 4 output-groups (16 outputs each); stats only in z==0 blocks.
// ROUND-8: channels 3-5 come from pts2 (one 16B gather) instead of 3 scalar
// gathers -> divergent loads per thread 40 -> 20. Same values, same op order
// -> q and stats bit-identical.
__global__ __launch_bounds__(256) void feat_kernel(const float4* __restrict__ pts,
                                                   const float4* __restrict__ pts2,
                                                   const float* __restrict__ W,
                                                   const int* __restrict__ idx,
                                                   float* __restrict__ q,
                                                   double* __restrict__ stats) {
    __shared__ float sW[COUT * CIN];
    __shared__ float sred[4][27];
    for (int i = threadIdx.x; i < COUT * CIN; i += 256) sW[i] = W[i];
    __syncthreads();

    int b = blockIdx.y;
    int og = blockIdx.z;           // output group: o in [16*og, 16*og+16)
    int n = blockIdx.x * 256 + threadIdx.x;
    const float4* p  = pts  + (size_t)b * NPTS;
    const float4* p2 = pts2 + (size_t)b * NPTS;

    int nb[K_NN];
#pragma unroll
    for (int k = 0; k < K_NN; k++) nb[k] = idx[((size_t)b * K_NN + k) * NPTS + n];

    float f[CIN][K_NN];
#pragma unroll
    for (int k = 0; k < K_NN; k++) {
        float4 c = p[nb[k]];                    // xyz in one 16B gather (doubled)
        f[0][k] = 0.5f * c.x; f[1][k] = 0.5f * c.y; f[2][k] = 0.5f * c.z;
    }
#pragma unroll
    for (int k = 0; k < K_NN; k++) {
        float4 c2 = p2[nb[k]];                  // ch 3-5 in one 16B gather
        f[3][k] = c2.x; f[4][k] = c2.y; f[5][k] = c2.z;
    }

    // center xyz over k, scale by 10
#pragma unroll
    for (int c = 0; c < 3; c++) {
        float s = 0.f;
#pragma unroll
        for (int k = 0; k < K_NN; k++) s += f[c][k];
        float m = s / 10.0f;
#pragma unroll
        for (int k = 0; k < K_NN; k++) f[c][k] = (f[c][k] - m) * 10.0f;
    }

    // q[b,o,n] = max_k y for this block's 16 outputs (same per-o op order)
    float* qb = q + (size_t)b * COUT * NPTS + n;
    int o0 = og * 16;
#pragma unroll
    for (int oo = 0; oo < 16; oo++) {
        int o = o0 + oo;
        float w0 = sW[o * 6 + 0], w1 = sW[o * 6 + 1], w2 = sW[o * 6 + 2];
        float w3 = sW[o * 6 + 3], w4 = sW[o * 6 + 4], w5 = sW[o * 6 + 5];
        float mx = -FLT_MAX;
#pragma unroll
        for (int k = 0; k < K_NN; k++) {
            float y = w0 * f[0][k] + w1 * f[1][k] + w2 * f[2][k] +
                      w3 * f[3][k] + w4 * f[4][k] + w5 * f[5][k];
            mx = fmaxf(mx, y);
        }
        qb[(size_t)o * NPTS] = mx;
    }

    if (og != 0) return;   // stats once (block-uniform branch; sync below safe)

    // moment stats: S1[6], S2[21]
    float s1[CIN];
#pragma unroll
    for (int c = 0; c < CIN; c++) {
        float s = 0.f;
#pragma unroll
        for (int k = 0; k < K_NN; k++) s += f[c][k];
        s1[c] = s;
    }
    float s2[21];
#pragma unroll
    for (int i = 0; i < 21; i++) s2[i] = 0.f;
#pragma unroll
    for (int k = 0; k < K_NN; k++) {
        int pp = 0;
#pragma unroll
        for (int c = 0; c < CIN; c++)
#pragma unroll
            for (int c2 = c; c2 < CIN; c2++) {
                s2[pp] += f[c][k] * f[c2][k];
                pp++;
            }
    }
#pragma unroll
    for (int c = 0; c < CIN; c++) s1[c] = wave_sum(s1[c]);
#pragma unroll
    for (int i = 0; i < 21; i++) s2[i] = wave_sum(s2[i]);

    int wv = threadIdx.x >> 6;
    int ln = threadIdx.x & 63;
    if (ln == 0) {
#pragma unroll
        for (int c = 0; c < CIN; c++) sred[wv][c] = s1[c];
#pragma unroll
        for (int i = 0; i < 21; i++) sred[wv][6 + i] = s2[i];
    }
    __syncthreads();
    if (threadIdx.x < 27) {
        float t = sred[0][threadIdx.x] + sred[1][threadIdx.x] +
                  sred[2][threadIdx.x] + sred[3][threadIdx.x];
        atomicAdd(&stats[threadIdx.x], (double)t);
    }
}

// ---- Kernel C: fold moments -> scale/shift (in-block); leaky; reduce max+mean ----
__global__ __launch_bounds__(256) void reduce_kernel(const float* __restrict__ q,
                                                     const double* __restrict__ stats,
                                                     const float* __restrict__ W,
                                                     const float* __restrict__ gamma,
                                                     const float* __restrict__ beta,
                                                     float* __restrict__ out) {
    int o = blockIdx.x;
    int b = blockIdx.y;

    __shared__ float s_sc, s_sh;
    if (threadIdx.x == 0) {
        const double minv = 1.0 / (double)((size_t)BATCH * NPTS * K_NN);
        double w[CIN];
#pragma unroll
        for (int c = 0; c < CIN; c++) w[c] = (double)W[o * CIN + c];
        double mu = 0.0;
#pragma unroll
        for (int c = 0; c < CIN; c++) mu += w[c] * stats[c];
        mu *= minv;
        double ey2 = 0.0;
        int pp = 6;
#pragma unroll
        for (int c = 0; c < CIN; c++)
#pragma unroll
            for (int c2 = c; c2 < CIN; c2++) {
                double v = w[c] * w[c2] * stats[pp];
                ey2 += (c2 == c) ? v : 2.0 * v;
                pp++;
            }
        ey2 *= minv;
        double var = ey2 - mu * mu;
        float scale = gamma[o] * rsqrtf((float)var + BN_EPS);
        float shift = beta[o] - (float)mu * scale;
        s_sc = scale;
        s_sh = shift;
    }
    __syncthreads();
    float scale = s_sc, shift = s_sh;

    const float* qp = q + ((size_t)b * COUT + o) * NPTS;
    float mx = -FLT_MAX, sm = 0.f;
    for (int i = threadIdx.x; i < NPTS; i += 256) {
        float z = scale * qp[i] + shift;
        z = (z >= 0.f) ? z : NEG_SLOPE * z;
        mx = fmaxf(mx, z);
        sm += z;
    }
    mx = wave_max(mx);
    sm = wave_sum(sm);
    __shared__ float smx[4], ssm2[4];
    int wv = threadIdx.x >> 6;
    int ln = threadIdx.x & 63;
    if (ln == 0) { smx[wv] = mx; ssm2[wv] = sm; }
    __syncthreads();
    if (threadIdx.x == 0) {
        float m = fmaxf(fmaxf(smx[0], smx[1]), fmaxf(smx[2], smx[3]));
        float s = ssm2[0] + ssm2[1] + ssm2[2] + ssm2[3];
        out[b * 2 * COUT + o] = m;
        out[b * 2 * COUT + COUT + o] = s * (1.0f / (float)NPTS);
    }
}

extern "C" void kernel_launch(void* const* d_in, const int* in_sizes, int n_in,
                              void* d_out, int out_size, void* d_ws, size_t ws_size,
                              hipStream_t stream) {
    const float* x     = (const float*)d_in[0];
    const float* W     = (const float*)d_in[1];
    const float* gamma = (const float*)d_in[2];
    const float* beta  = (const float*)d_in[3];
    float* out = (float*)d_out;

    char* ws = (char*)d_ws;
    int*    idx   = (int*)(ws + OFF_IDX);
    float4* pts   = (float4*)(ws + OFF_PTS);
    float4* pts2  = (float4*)(ws + OFF_PTS2);
    int*    part  = (int*)(ws + OFF_Q);     // aliases q region (consumed before q written)
    float*  q     = (float*)(ws + OFF_Q);
    double* stats = (double*)(ws + OFF_ST);

    prep_pts<<<BATCH * NPTS / 256, 256, 0, stream>>>(x, pts, pts2, stats);
    knn_part<<<dim3(NPTS / 256, BATCH, NSEG), 256, 0, stream>>>(pts, part);
    merge_kernel<<<dim3(NPTS / 64, BATCH), 512, 0, stream>>>(pts, part, idx);
    feat_kernel<<<dim3(NPTS / 256, BATCH, 4), 256, 0, stream>>>(pts, pts2, W, idx, q, stats);
    reduce_kernel<<<dim3(COUT, BATCH), 256, 0, stream>>>(q, stats, W, gamma, beta, out);
}

// Round 9
// 165.715 us; speedup vs baseline: 1.1710x; 1.1013x over previous
//
#include <hip/hip_runtime.h>
#include <float.h>

#define K_NN 10
#define BATCH 8
#define CIN 6
#define NPTS 4096
#define COUT 64
#define NSEG 8
#define SEGLEN (NPTS / NSEG)    // 512
#define CHUNK 16
#define NCHUNK (SEGLEN / CHUNK) // 32
#define NWORD (SEGLEN / 32)     // 16
#define NEG_SLOPE 0.2f
#define BN_EPS 1e-5f

// ---- workspace layout (bytes) ----
// ROUND-9: part/idx eliminated by fusion -> no aliasing, 9.4 MB total.
static constexpr size_t OFF_PTS  = 0;                                                    // float4[8*4096] (2x,2y,2z,|p|^2)
static constexpr size_t OFF_PTS2 = OFF_PTS + (size_t)BATCH * NPTS * sizeof(float4);      // float4[8*4096] (x3,x4,x5,0)
static constexpr size_t OFF_Q    = OFF_PTS2 + (size_t)BATCH * NPTS * sizeof(float4);     // float[8*64*4096]
static constexpr size_t OFF_ST   = OFF_Q + (size_t)BATCH * COUT * NPTS * sizeof(float);  // double[27]

__device__ __forceinline__ float wave_sum(float v) {
#pragma unroll
    for (int m = 32; m >= 1; m >>= 1) v += __shfl_xor(v, m, 64);
    return v;
}
__device__ __forceinline__ float wave_max(float v) {
#pragma unroll
    for (int m = 32; m >= 1; m >>= 1) v = fmaxf(v, __shfl_xor(v, m, 64));
    return v;
}

// pts stores (2x, 2y, 2z, ||p||^2); query coords pre-halved once per thread.
// d' = 2*inner - ||c||^2 -> 3 FMAs. Monotone shift of true distance, used
// consistently in knn/drain/merge. DO NOT reorder (bit-stable).
__device__ __forceinline__ float distp(float qx, float qy, float qz, float4 c) {
    return fmaf(c.x, qx, fmaf(c.y, qy, fmaf(c.z, qz, -c.w)));
}

__device__ __forceinline__ float fmax3(float a, float b, float c) {
    return fmaxf(fmaxf(a, b), c);   // fuses to v_max3_f32 (exact for non-NaN)
}

// 10-deep chunk-max chain level
#define CHL(cj) { float _hi = fmaxf(cj, t); t = fminf(cj, t); cj = _hi; }

// one conditional swap level of the insertion sort
#define CSWP(va, vb, ia, ib) \
    if (va > vb) { float _tv = va; va = vb; vb = _tv; int _ti = ia; ia = ib; ib = _ti; }

// exact strict-> insertion of (d,m) into descending list v0..v9 / i0..i9
#define INSERT10(dd, mm) \
    if ((dd) > v9) { \
        v9 = (dd); i9 = (mm); \
        CSWP(v9, v8, i9, i8) \
        CSWP(v8, v7, i8, i7) \
        CSWP(v7, v6, i7, i6) \
        CSWP(v6, v5, i6, i5) \
        CSWP(v5, v4, i5, i4) \
        CSWP(v4, v3, i4, i3) \
        CSWP(v3, v2, i3, i2) \
        CSWP(v2, v1, i2, i1) \
        CSWP(v1, v0, i1, i0) \
    }

// ---- Kernel P: pack pts (2x,2y,2z,|p|^2) + pts2 (x3,x4,x5); zero stats ----
__global__ __launch_bounds__(256) void prep_pts(const float* __restrict__ x,
                                                float4* __restrict__ pts,
                                                float4* __restrict__ pts2,
                                                double* __restrict__ stats) {
    if (blockIdx.x == 0 && threadIdx.x < 27) stats[threadIdx.x] = 0.0;
    int t = blockIdx.x * 256 + threadIdx.x;   // 0..32767
    int b = t >> 12;
    int n = t & (NPTS - 1);
    const float* xb = x + (size_t)b * CIN * NPTS;
    float x0 = xb[n];
    float x1 = xb[NPTS + n];
    float x2 = xb[2 * NPTS + n];
    pts[t] = make_float4(2.0f * x0, 2.0f * x1, 2.0f * x2, x0 * x0 + x1 * x1 + x2 * x2);
    float x3 = xb[3 * NPTS + n];
    float x4 = xb[4 * NPTS + n];
    float x5 = xb[5 * NPTS + n];
    pts2[t] = make_float4(x3, x4, x5, 0.0f);
}

// ---- Kernel A: FUSED knn + merge + feat ----
// Block = 8 waves x 64 queries.  Grid (NPTS/64, BATCH) = 512 blocks.
// Phase A: wave w runs the FROZEN knn body (r4/r6/r8, ~79us floor) on
//          segment w for the block's 64 queries. Per-wave workload and
//          selection arithmetic bit-identical to the standalone knn_part
//          (s == wvu, uniform scalar candidate loads). 4096 wave-workloads,
//          4 waves/SIMD -- unchanged.
// Phase B: LDS publish; wave 0 merges 8x10 in (s asc, j asc) == ascending
//          candidate order (r3/r6/r8-proven tie semantics) -> idxL in LDS.
//          part[] / idx[] global round-trips (21+ MB) eliminated.
// Phase C: wave w computes q channels [8w,8w+8) for the 64 queries (r8 feat
//          arithmetic, per-(o,n) op order identical -> q bit-identical).
//          Wave 0 additionally computes moment stats (regrouped: 64-query
//          wave sums, double atomics -- strictly more accurate than the old
//          float pre-sum of 4 wave sums; tiny absmax shift accepted).
__global__ __launch_bounds__(512, 4) void knnmf_kernel(const float4* __restrict__ pts,
                                                       const float4* __restrict__ pts2,
                                                       const float* __restrict__ W,
                                                       float* __restrict__ q,
                                                       double* __restrict__ stats) {
    __shared__ float dml[NSEG][K_NN][64];            // 20 KB
    __shared__ unsigned short iml[NSEG][K_NN][64];   // 10 KB
    __shared__ unsigned short idxL[K_NN][64];        // 1.25 KB
    __shared__ float sW[COUT * CIN];                 // 1.5 KB
    __shared__ float sstat[27];

    for (int i = threadIdx.x; i < COUT * CIN; i += 512) sW[i] = W[i];

    int b  = blockIdx.y;
    int ln = threadIdx.x & 63;
    int wv = threadIdx.x >> 6;
    int wvu = __builtin_amdgcn_readfirstlane(wv);   // uniform (round-2 lesson)
    int n  = blockIdx.x * 64 + ln;
    const float4* p = pts + (size_t)b * NPTS;       // uniform base -> scalar loads
    float4 q4 = p[n];
    float qx = 0.5f * q4.x, qy = 0.5f * q4.y, qz = 0.5f * q4.z;
    int m0 = wvu * SEGLEN;                          // UNIFORM segment base

    // ================= Phase A: frozen knn body, segment wvu =================
    {
        float c0 = -FLT_MAX, c1 = -FLT_MAX, c2 = -FLT_MAX, c3 = -FLT_MAX, c4 = -FLT_MAX;
        float c5 = -FLT_MAX, c6 = -FLT_MAX, c7 = -FLT_MAX, c8 = -FLT_MAX, c9 = -FLT_MAX;

        for (int ch = 0; ch < NCHUNK; ch++) {
            const float4* cp = p + (m0 + ch * CHUNK);
            float d0  = distp(qx, qy, qz, cp[0]);
            float d1  = distp(qx, qy, qz, cp[1]);
            float d2  = distp(qx, qy, qz, cp[2]);
            float d3  = distp(qx, qy, qz, cp[3]);
            float d4  = distp(qx, qy, qz, cp[4]);
            float d5  = distp(qx, qy, qz, cp[5]);
            float d6  = distp(qx, qy, qz, cp[6]);
            float d7  = distp(qx, qy, qz, cp[7]);
            float d8  = distp(qx, qy, qz, cp[8]);
            float d9  = distp(qx, qy, qz, cp[9]);
            float d10 = distp(qx, qy, qz, cp[10]);
            float d11 = distp(qx, qy, qz, cp[11]);
            float d12 = distp(qx, qy, qz, cp[12]);
            float d13 = distp(qx, qy, qz, cp[13]);
            float d14 = distp(qx, qy, qz, cp[14]);
            float d15 = distp(qx, qy, qz, cp[15]);
            float a0 = fmax3(d0, d1, d2);
            float a1 = fmax3(d3, d4, d5);
            float a2 = fmax3(d6, d7, d8);
            float a3 = fmax3(d9, d10, d11);
            float a4 = fmax3(d12, d13, d14);
            float t = fmaxf(fmax3(fmax3(a0, a1, a2), a3, a4), d15);
            CHL(c0) CHL(c1) CHL(c2) CHL(c3) CHL(c4)
            CHL(c5) CHL(c6) CHL(c7) CHL(c8) CHL(c9)
        }
        float thr = c9;   // 10th-largest chunk max (<= exact v10)

        float v0 = -FLT_MAX, v1 = -FLT_MAX, v2 = -FLT_MAX, v3 = -FLT_MAX, v4 = -FLT_MAX;
        float v5 = -FLT_MAX, v6 = -FLT_MAX, v7 = -FLT_MAX, v8 = -FLT_MAX, v9 = -FLT_MAX;
        int i0 = 0, i1 = 0, i2 = 0, i3 = 0, i4 = 0;
        int i5 = 0, i6 = 0, i7 = 0, i8 = 0, i9 = 0;

        for (int w = 0; w < NWORD; w++) {
            const float4* cp = p + (m0 + w * 32);
            unsigned int mask = 0u;
#pragma unroll
            for (int u = 0; u < 32; u++) {
                float d = distp(qx, qy, qz, cp[u]);
                mask = (mask << 1) | (d >= thr ? 1u : 0u);   // point u -> bit (31-u)
            }
            int base = m0 + w * 32;
            while (mask) {
                int j = __builtin_clz(mask);        // MSB-first == ascending m
                mask ^= (0x80000000u >> j);
                int m = base + j;
                float4 cc = p[m];                   // divergent, L1-hot
                float d = distp(qx, qy, qz, cc);
                INSERT10(d, m)
            }
        }

        // ---- Phase B publish ----
        dml[wv][0][ln] = v0; iml[wv][0][ln] = (unsigned short)i0;
        dml[wv][1][ln] = v1; iml[wv][1][ln] = (unsigned short)i1;
        dml[wv][2][ln] = v2; iml[wv][2][ln] = (unsigned short)i2;
        dml[wv][3][ln] = v3; iml[wv][3][ln] = (unsigned short)i3;
        dml[wv][4][ln] = v4; iml[wv][4][ln] = (unsigned short)i4;
        dml[wv][5][ln] = v5; iml[wv][5][ln] = (unsigned short)i5;
        dml[wv][6][ln] = v6; iml[wv][6][ln] = (unsigned short)i6;
        dml[wv][7][ln] = v7; iml[wv][7][ln] = (unsigned short)i7;
        dml[wv][8][ln] = v8; iml[wv][8][ln] = (unsigned short)i8;
        dml[wv][9][ln] = v9; iml[wv][9][ln] = (unsigned short)i9;
    }
    __syncthreads();

    // ---- Phase B: wave 0 merges 8x10 -> idxL (s asc, j asc order) ----
    if (wvu == 0) {
        float v0 = -FLT_MAX, v1 = -FLT_MAX, v2 = -FLT_MAX, v3 = -FLT_MAX, v4 = -FLT_MAX;
        float v5 = -FLT_MAX, v6 = -FLT_MAX, v7 = -FLT_MAX, v8 = -FLT_MAX, v9 = -FLT_MAX;
        int i0 = 0, i1 = 0, i2 = 0, i3 = 0, i4 = 0;
        int i5 = 0, i6 = 0, i7 = 0, i8 = 0, i9 = 0;
#pragma unroll
        for (int w = 0; w < NSEG; w++) {
#pragma unroll
            for (int j = 0; j < K_NN; j++) {
                float d = dml[w][j][ln];
                int m = iml[w][j][ln];
                INSERT10(d, m)
            }
        }
        idxL[0][ln] = (unsigned short)i0;
        idxL[1][ln] = (unsigned short)i1;
        idxL[2][ln] = (unsigned short)i2;
        idxL[3][ln] = (unsigned short)i3;
        idxL[4][ln] = (unsigned short)i4;
        idxL[5][ln] = (unsigned short)i5;
        idxL[6][ln] = (unsigned short)i6;
        idxL[7][ln] = (unsigned short)i7;
        idxL[8][ln] = (unsigned short)i8;
        idxL[9][ln] = (unsigned short)i9;
    }
    __syncthreads();

    // ================= Phase C: feat (wave w -> channels [8w, 8w+8)) ========
    const float4* p2 = pts2 + (size_t)b * NPTS;

    int nb[K_NN];
#pragma unroll
    for (int k = 0; k < K_NN; k++) nb[k] = idxL[k][ln];

    float f[CIN][K_NN];
#pragma unroll
    for (int k = 0; k < K_NN; k++) {
        float4 c = p[nb[k]];                    // xyz in one 16B gather (doubled)
        f[0][k] = 0.5f * c.x; f[1][k] = 0.5f * c.y; f[2][k] = 0.5f * c.z;
    }
#pragma unroll
    for (int k = 0; k < K_NN; k++) {
        float4 c2 = p2[nb[k]];                  // ch 3-5 in one 16B gather
        f[3][k] = c2.x; f[4][k] = c2.y; f[5][k] = c2.z;
    }

    // center xyz over k, scale by 10
#pragma unroll
    for (int c = 0; c < 3; c++) {
        float s = 0.f;
#pragma unroll
        for (int k = 0; k < K_NN; k++) s += f[c][k];
        float m = s / 10.0f;
#pragma unroll
        for (int k = 0; k < K_NN; k++) f[c][k] = (f[c][k] - m) * 10.0f;
    }

    // q[b,o,n] = max_k y, 8 channels per wave (same per-(o,n) op order)
    float* qb = q + (size_t)b * COUT * NPTS + n;
    int o0 = wvu * 8;
#pragma unroll
    for (int oo = 0; oo < 8; oo++) {
        int o = o0 + oo;
        float w0 = sW[o * 6 + 0], w1 = sW[o * 6 + 1], w2 = sW[o * 6 + 2];
        float w3 = sW[o * 6 + 3], w4 = sW[o * 6 + 4], w5 = sW[o * 6 + 5];
        float mx = -FLT_MAX;
#pragma unroll
        for (int k = 0; k < K_NN; k++) {
            float y = w0 * f[0][k] + w1 * f[1][k] + w2 * f[2][k] +
                      w3 * f[3][k] + w4 * f[4][k] + w5 * f[5][k];
            mx = fmaxf(mx, y);
        }
        qb[(size_t)o * NPTS] = mx;
    }

    // ---- stats: wave 0 only (64-query wave sums, double atomics) ----
    if (wvu == 0) {
        float s1[CIN];
#pragma unroll
        for (int c = 0; c < CIN; c++) {
            float s = 0.f;
#pragma unroll
            for (int k = 0; k < K_NN; k++) s += f[c][k];
            s1[c] = s;
        }
        float s2[21];
#pragma unroll
        for (int i = 0; i < 21; i++) s2[i] = 0.f;
#pragma unroll
        for (int k = 0; k < K_NN; k++) {
            int pp = 0;
#pragma unroll
            for (int c = 0; c < CIN; c++)
#pragma unroll
                for (int c2 = c; c2 < CIN; c2++) {
                    s2[pp] += f[c][k] * f[c2][k];
                    pp++;
                }
        }
#pragma unroll
        for (int c = 0; c < CIN; c++) s1[c] = wave_sum(s1[c]);
#pragma unroll
        for (int i = 0; i < 21; i++) s2[i] = wave_sum(s2[i]);

        if (ln == 0) {
#pragma unroll
            for (int c = 0; c < CIN; c++) sstat[c] = s1[c];
#pragma unroll
            for (int i = 0; i < 21; i++) sstat[6 + i] = s2[i];
        }
        // same-wave LDS write->read: compiler orders via lgkmcnt (no barrier;
        // waves 1-7 may already have exited)
        if (ln < 27) atomicAdd(&stats[ln], (double)sstat[ln]);
    }
}

// ---- Kernel C: fold moments -> scale/shift (in-block); leaky; reduce max+mean ----
__global__ __launch_bounds__(256) void reduce_kernel(const float* __restrict__ q,
                                                     const double* __restrict__ stats,
                                                     const float* __restrict__ W,
                                                     const float* __restrict__ gamma,
                                                     const float* __restrict__ beta,
                                                     float* __restrict__ out) {
    int o = blockIdx.x;
    int b = blockIdx.y;

    __shared__ float s_sc, s_sh;
    if (threadIdx.x == 0) {
        const double minv = 1.0 / (double)((size_t)BATCH * NPTS * K_NN);
        double w[CIN];
#pragma unroll
        for (int c = 0; c < CIN; c++) w[c] = (double)W[o * CIN + c];
        double mu = 0.0;
#pragma unroll
        for (int c = 0; c < CIN; c++) mu += w[c] * stats[c];
        mu *= minv;
        double ey2 = 0.0;
        int pp = 6;
#pragma unroll
        for (int c = 0; c < CIN; c++)
#pragma unroll
            for (int c2 = c; c2 < CIN; c2++) {
                double v = w[c] * w[c2] * stats[pp];
                ey2 += (c2 == c) ? v : 2.0 * v;
                pp++;
            }
        ey2 *= minv;
        double var = ey2 - mu * mu;
        float scale = gamma[o] * rsqrtf((float)var + BN_EPS);
        float shift = beta[o] - (float)mu * scale;
        s_sc = scale;
        s_sh = shift;
    }
    __syncthreads();
    float scale = s_sc, shift = s_sh;

    const float* qp = q + ((size_t)b * COUT + o) * NPTS;
    float mx = -FLT_MAX, sm = 0.f;
    for (int i = threadIdx.x; i < NPTS; i += 256) {
        float z = scale * qp[i] + shift;
        z = (z >= 0.f) ? z : NEG_SLOPE * z;
        mx = fmaxf(mx, z);
        sm += z;
    }
    mx = wave_max(mx);
    sm = wave_sum(sm);
    __shared__ float smx[4], ssm2[4];
    int wv = threadIdx.x >> 6;
    int ln = threadIdx.x & 63;
    if (ln == 0) { smx[wv] = mx; ssm2[wv] = sm; }
    __syncthreads();
    if (threadIdx.x == 0) {
        float m = fmaxf(fmaxf(smx[0], smx[1]), fmaxf(smx[2], smx[3]));
        float s = ssm2[0] + ssm2[1] + ssm2[2] + ssm2[3];
        out[b * 2 * COUT + o] = m;
        out[b * 2 * COUT + COUT + o] = s * (1.0f / (float)NPTS);
    }
}

extern "C" void kernel_launch(void* const* d_in, const int* in_sizes, int n_in,
                              void* d_out, int out_size, void* d_ws, size_t ws_size,
                              hipStream_t stream) {
    const float* x     = (const float*)d_in[0];
    const float* W     = (const float*)d_in[1];
    const float* gamma = (const float*)d_in[2];
    const float* beta  = (const float*)d_in[3];
    float* out = (float*)d_out;

    char* ws = (char*)d_ws;
    float4* pts   = (float4*)(ws + OFF_PTS);
    float4* pts2  = (float4*)(ws + OFF_PTS2);
    float*  q     = (float*)(ws + OFF_Q);
    double* stats = (double*)(ws + OFF_ST);

    prep_pts<<<BATCH * NPTS / 256, 256, 0, stream>>>(x, pts, pts2, stats);
    knnmf_kernel<<<dim3(NPTS / 64, BATCH), 512, 0, stream>>>(pts, pts2, W, q, stats);
    reduce_kernel<<<dim3(COUT, BATCH), 256, 0, stream>>>(q, stats, W, gamma, beta, out);
}

// Round 10
// 163.751 us; speedup vs baseline: 1.1851x; 1.0120x over previous
//
#include <hip/hip_runtime.h>
#include <float.h>

#define K_NN 10
#define BATCH 8
#define CIN 6
#define NPTS 4096
#define COUT 64
#define NSEG 8
#define SEGLEN (NPTS / NSEG)    // 512
#define CHUNK 16
#define NCHUNK (SEGLEN / CHUNK) // 32
#define NWORD (SEGLEN / 32)     // 16
#define NEG_SLOPE 0.2f
#define BN_EPS 1e-5f

// ---- workspace layout (bytes) ----
static constexpr size_t OFF_PTS  = 0;                                                    // float4[8*4096] (2x,2y,2z,|p|^2)
static constexpr size_t OFF_PTS2 = OFF_PTS + (size_t)BATCH * NPTS * sizeof(float4);      // float4[8*4096] (x3,x4,x5,0)
static constexpr size_t OFF_PTSP = OFF_PTS2 + (size_t)BATCH * NPTS * sizeof(float4);     // float4[8*4096] pair-interleaved
static constexpr size_t OFF_Q    = OFF_PTSP + (size_t)BATCH * NPTS * sizeof(float4);     // float[8*64*4096]
static constexpr size_t OFF_ST   = OFF_Q + (size_t)BATCH * COUT * NPTS * sizeof(float);  // double[27]

typedef float v2f __attribute__((ext_vector_type(2)));

__device__ __forceinline__ float wave_sum(float v) {
#pragma unroll
    for (int m = 32; m >= 1; m >>= 1) v += __shfl_xor(v, m, 64);
    return v;
}
__device__ __forceinline__ float wave_max(float v) {
#pragma unroll
    for (int m = 32; m >= 1; m >>= 1) v = fmaxf(v, __shfl_xor(v, m, 64));
    return v;
}

// pts stores (2x, 2y, 2z, ||p||^2); query coords pre-halved once per thread.
// d' = 2*inner - ||c||^2 -> 3 FMAs. Monotone shift of true distance, used
// consistently in knn/drain/merge. DO NOT reorder (bit-stable).
__device__ __forceinline__ float distp(float qx, float qy, float qz, float4 c) {
    return fmaf(c.x, qx, fmaf(c.y, qy, fmaf(c.z, qz, -c.w)));
}

// Packed pair distance: fa=(x0,x1,y0,y1), fb=(z0,z1,w0,w1) (pre-doubled xyz).
// Identical fma chain per element as distp -> BIT-IDENTICAL (r7-verified,
// absmax 0.0); lowers to v_pk_fma_f32 on gfx950.
__device__ __forceinline__ v2f dist2(v2f qx2, v2f qy2, v2f qz2, float4 fa, float4 fb) {
    v2f cx = {fa.x, fa.y}, cy = {fa.z, fa.w}, cz = {fb.x, fb.y}, cw = {fb.z, fb.w};
#if __has_builtin(__builtin_elementwise_fma)
    v2f t = __builtin_elementwise_fma(cz, qz2, -cw);
    t = __builtin_elementwise_fma(cy, qy2, t);
    t = __builtin_elementwise_fma(cx, qx2, t);
    return t;
#else
    v2f t;
    t[0] = fmaf(cx[0], qx2[0], fmaf(cy[0], qy2[0], fmaf(cz[0], qz2[0], -cw[0])));
    t[1] = fmaf(cx[1], qx2[1], fmaf(cy[1], qy2[1], fmaf(cz[1], qz2[1], -cw[1])));
    return t;
#endif
}

__device__ __forceinline__ v2f vmax2(v2f a, v2f b) {
#if __has_builtin(__builtin_elementwise_max)
    return __builtin_elementwise_max(a, b);   // v_pk_max_f32
#else
    v2f r; r[0] = fmaxf(a[0], b[0]); r[1] = fmaxf(a[1], b[1]); return r;
#endif
}

// 10-deep chunk-max chain level
#define CHL(cj) { float _hi = fmaxf(cj, t); t = fminf(cj, t); cj = _hi; }

// one conditional swap level of the insertion sort
#define CSWP(va, vb, ia, ib) \
    if (va > vb) { float _tv = va; va = vb; vb = _tv; int _ti = ia; ia = ib; ib = _ti; }

// exact strict-> insertion of (d,m) into descending list v0..v9 / i0..i9
#define INSERT10(dd, mm) \
    if ((dd) > v9) { \
        v9 = (dd); i9 = (mm); \
        CSWP(v9, v8, i9, i8) \
        CSWP(v8, v7, i8, i7) \
        CSWP(v7, v6, i7, i6) \
        CSWP(v6, v5, i6, i5) \
        CSWP(v5, v4, i5, i4) \
        CSWP(v4, v3, i4, i3) \
        CSWP(v3, v2, i3, i2) \
        CSWP(v2, v1, i2, i1) \
        CSWP(v1, v0, i1, i0) \
    }

// ---- Kernel P: pack pts / pts2 / ptsp (pair-interleaved); zero stats ----
__global__ __launch_bounds__(256) void prep_pts(const float* __restrict__ x,
                                                float4* __restrict__ pts,
                                                float4* __restrict__ pts2,
                                                float4* __restrict__ ptsp,
                                                double* __restrict__ stats) {
    if (blockIdx.x == 0 && threadIdx.x < 27) stats[threadIdx.x] = 0.0;
    int t = blockIdx.x * 256 + threadIdx.x;   // 0..32767
    int b = t >> 12;
    int n = t & (NPTS - 1);
    const float* xb = x + (size_t)b * CIN * NPTS;
    float X = xb[n];
    float Y = xb[NPTS + n];
    float Z = xb[2 * NPTS + n];
    float w = X * X + Y * Y + Z * Z;
    pts[t] = make_float4(2.0f * X, 2.0f * Y, 2.0f * Z, w);
    float x3 = xb[3 * NPTS + n];
    float x4 = xb[4 * NPTS + n];
    float x5 = xb[5 * NPTS + n];
    pts2[t] = make_float4(x3, x4, x5, 0.0f);
    // neighbor (n+1) via shuffle; even lanes write the pair record (n parity
    // == lane parity: shfl_down(1) valid). r7-verified.
    float Xn = __shfl_down(X, 1, 64);
    float Yn = __shfl_down(Y, 1, 64);
    float Zn = __shfl_down(Z, 1, 64);
    float wn = __shfl_down(w, 1, 64);
    if ((n & 1) == 0) {
        float4* pb = ptsp + (size_t)b * NPTS;
        pb[n]     = make_float4(2.0f * X, 2.0f * Xn, 2.0f * Y, 2.0f * Yn);
        pb[n + 1] = make_float4(2.0f * Z, 2.0f * Zn, w, wn);
    }
}

// ---- Kernel A: FUSED knn + merge + feat ----
// Block = 8 waves x 64 queries.  Grid (NPTS/64, BATCH) = 512 blocks.
// Phase A: wave w runs the knn body on segment w: PACKED (v_pk_fma_f32)
//          distance passes over ptsp (r10; bit-identical values to the frozen
//          scalar body, r7-proven), bitmask+clz drain over pts (r4-frozen).
//          Same thr, same selection, same tie semantics.
// Phase B: LDS publish; wave 0 merges 8x10 in (s asc, j asc) == ascending
//          candidate order (r3/r6/r8-proven) -> idxL in LDS.
// Phase C: wave w computes q channels [8w,8w+8) (r8 feat arithmetic,
//          bit-identical q); wave 0 computes moment stats (double atomics).
__global__ __launch_bounds__(512, 4) void knnmf_kernel(const float4* __restrict__ pts,
                                                       const float4* __restrict__ pts2,
                                                       const float4* __restrict__ ptsp,
                                                       const float* __restrict__ W,
                                                       float* __restrict__ q,
                                                       double* __restrict__ stats) {
    __shared__ float dml[NSEG][K_NN][64];            // 20 KB
    __shared__ unsigned short iml[NSEG][K_NN][64];   // 10 KB
    __shared__ unsigned short idxL[K_NN][64];        // 1.25 KB
    __shared__ float sW[COUT * CIN];                 // 1.5 KB
    __shared__ float sstat[27];

    for (int i = threadIdx.x; i < COUT * CIN; i += 512) sW[i] = W[i];

    int b  = blockIdx.y;
    int ln = threadIdx.x & 63;
    int wv = threadIdx.x >> 6;
    int wvu = __builtin_amdgcn_readfirstlane(wv);   // uniform (round-2 lesson)
    int n  = blockIdx.x * 64 + ln;
    const float4* p   = pts  + (size_t)b * NPTS;    // uniform base -> scalar loads
    const float4* p2s = ptsp + (size_t)b * NPTS;
    float4 q4 = p[n];
    float qx = 0.5f * q4.x, qy = 0.5f * q4.y, qz = 0.5f * q4.z;
    v2f qx2 = {qx, qx}, qy2 = {qy, qy}, qz2 = {qz, qz};
    int m0 = wvu * SEGLEN;                          // UNIFORM segment base

    // ================= Phase A: knn body, segment wvu =================
    {
        // ---- pass 1: threshold from chunk maxima (packed, 8 pairs/chunk) ----
        float c0 = -FLT_MAX, c1 = -FLT_MAX, c2 = -FLT_MAX, c3 = -FLT_MAX, c4 = -FLT_MAX;
        float c5 = -FLT_MAX, c6 = -FLT_MAX, c7 = -FLT_MAX, c8 = -FLT_MAX, c9 = -FLT_MAX;

        for (int ch = 0; ch < NCHUNK; ch++) {
            const float4* cp = p2s + (m0 + ch * CHUNK);   // 16 float4 = 8 pairs
            v2f e0 = dist2(qx2, qy2, qz2, cp[0],  cp[1]);
            v2f e1 = dist2(qx2, qy2, qz2, cp[2],  cp[3]);
            v2f e2 = dist2(qx2, qy2, qz2, cp[4],  cp[5]);
            v2f e3 = dist2(qx2, qy2, qz2, cp[6],  cp[7]);
            v2f e4 = dist2(qx2, qy2, qz2, cp[8],  cp[9]);
            v2f e5 = dist2(qx2, qy2, qz2, cp[10], cp[11]);
            v2f e6 = dist2(qx2, qy2, qz2, cp[12], cp[13]);
            v2f e7 = dist2(qx2, qy2, qz2, cp[14], cp[15]);
            v2f a0 = vmax2(e0, e1);
            v2f a1 = vmax2(e2, e3);
            v2f a2 = vmax2(e4, e5);
            v2f a3 = vmax2(e6, e7);
            v2f b0 = vmax2(a0, a1);
            v2f b1 = vmax2(a2, a3);
            v2f cm = vmax2(b0, b1);
            float t = fmaxf(cm[0], cm[1]);        // exact: max reorder-invariant
            CHL(c0) CHL(c1) CHL(c2) CHL(c3) CHL(c4)
            CHL(c5) CHL(c6) CHL(c7) CHL(c8) CHL(c9)
        }
        float thr = c9;   // 10th-largest chunk max (<= exact v10) -- same value as r9

        // ---- pass 2 + drain: bitmask survivors (packed), exact insert ----
        float v0 = -FLT_MAX, v1 = -FLT_MAX, v2 = -FLT_MAX, v3 = -FLT_MAX, v4 = -FLT_MAX;
        float v5 = -FLT_MAX, v6 = -FLT_MAX, v7 = -FLT_MAX, v8 = -FLT_MAX, v9 = -FLT_MAX;
        int i0 = 0, i1 = 0, i2 = 0, i3 = 0, i4 = 0;
        int i5 = 0, i6 = 0, i7 = 0, i8 = 0, i9 = 0;

        for (int w = 0; w < NWORD; w++) {
            const float4* cp = p2s + (m0 + w * 32);   // 32 pts = 16 pairs
            unsigned int mask = 0u;
#pragma unroll
            for (int pr = 0; pr < 16; pr++) {
                v2f d2v = dist2(qx2, qy2, qz2, cp[2 * pr], cp[2 * pr + 1]);
                // point 2pr -> higher bit, 2pr+1 -> lower: bit(31-u) = point u
                mask = (mask << 2) | (d2v[0] >= thr ? 2u : 0u) | (d2v[1] >= thr ? 1u : 0u);
            }
            int base = m0 + w * 32;
            while (mask) {
                int j = __builtin_clz(mask);        // MSB-first == ascending m
                mask ^= (0x80000000u >> j);
                int m = base + j;
                float4 cc = p[m];                   // divergent, L1-hot
                float d = distp(qx, qy, qz, cc);
                INSERT10(d, m)
            }
        }

        // ---- Phase B publish ----
        dml[wv][0][ln] = v0; iml[wv][0][ln] = (unsigned short)i0;
        dml[wv][1][ln] = v1; iml[wv][1][ln] = (unsigned short)i1;
        dml[wv][2][ln] = v2; iml[wv][2][ln] = (unsigned short)i2;
        dml[wv][3][ln] = v3; iml[wv][3][ln] = (unsigned short)i3;
        dml[wv][4][ln] = v4; iml[wv][4][ln] = (unsigned short)i4;
        dml[wv][5][ln] = v5; iml[wv][5][ln] = (unsigned short)i5;
        dml[wv][6][ln] = v6; iml[wv][6][ln] = (unsigned short)i6;
        dml[wv][7][ln] = v7; iml[wv][7][ln] = (unsigned short)i7;
        dml[wv][8][ln] = v8; iml[wv][8][ln] = (unsigned short)i8;
        dml[wv][9][ln] = v9; iml[wv][9][ln] = (unsigned short)i9;
    }
    __syncthreads();

    // ---- Phase B: wave 0 merges 8x10 -> idxL (s asc, j asc order) ----
    if (wvu == 0) {
        float v0 = -FLT_MAX, v1 = -FLT_MAX, v2 = -FLT_MAX, v3 = -FLT_MAX, v4 = -FLT_MAX;
        float v5 = -FLT_MAX, v6 = -FLT_MAX, v7 = -FLT_MAX, v8 = -FLT_MAX, v9 = -FLT_MAX;
        int i0 = 0, i1 = 0, i2 = 0, i3 = 0, i4 = 0;
        int i5 = 0, i6 = 0, i7 = 0, i8 = 0, i9 = 0;
#pragma unroll
        for (int w = 0; w < NSEG; w++) {
#pragma unroll
            for (int j = 0; j < K_NN; j++) {
                float d = dml[w][j][ln];
                int m = iml[w][j][ln];
                INSERT10(d, m)
            }
        }
        idxL[0][ln] = (unsigned short)i0;
        idxL[1][ln] = (unsigned short)i1;
        idxL[2][ln] = (unsigned short)i2;
        idxL[3][ln] = (unsigned short)i3;
        idxL[4][ln] = (unsigned short)i4;
        idxL[5][ln] = (unsigned short)i5;
        idxL[6][ln] = (unsigned short)i6;
        idxL[7][ln] = (unsigned short)i7;
        idxL[8][ln] = (unsigned short)i8;
        idxL[9][ln] = (unsigned short)i9;
    }
    __syncthreads();

    // ================= Phase C: feat (wave w -> channels [8w, 8w+8)) ========
    const float4* p2 = pts2 + (size_t)b * NPTS;

    int nb[K_NN];
#pragma unroll
    for (int k = 0; k < K_NN; k++) nb[k] = idxL[k][ln];

    float f[CIN][K_NN];
#pragma unroll
    for (int k = 0; k < K_NN; k++) {
        float4 c = p[nb[k]];                    // xyz in one 16B gather (doubled)
        f[0][k] = 0.5f * c.x; f[1][k] = 0.5f * c.y; f[2][k] = 0.5f * c.z;
    }
#pragma unroll
    for (int k = 0; k < K_NN; k++) {
        float4 c2 = p2[nb[k]];                  // ch 3-5 in one 16B gather
        f[3][k] = c2.x; f[4][k] = c2.y; f[5][k] = c2.z;
    }

    // center xyz over k, scale by 10
#pragma unroll
    for (int c = 0; c < 3; c++) {
        float s = 0.f;
#pragma unroll
        for (int k = 0; k < K_NN; k++) s += f[c][k];
        float m = s / 10.0f;
#pragma unroll
        for (int k = 0; k < K_NN; k++) f[c][k] = (f[c][k] - m) * 10.0f;
    }

    // q[b,o,n] = max_k y, 8 channels per wave (same per-(o,n) op order)
    float* qb = q + (size_t)b * COUT * NPTS + n;
    int o0 = wvu * 8;
#pragma unroll
    for (int oo = 0; oo < 8; oo++) {
        int o = o0 + oo;
        float w0 = sW[o * 6 + 0], w1 = sW[o * 6 + 1], w2 = sW[o * 6 + 2];
        float w3 = sW[o * 6 + 3], w4 = sW[o * 6 + 4], w5 = sW[o * 6 + 5];
        float mx = -FLT_MAX;
#pragma unroll
        for (int k = 0; k < K_NN; k++) {
            float y = w0 * f[0][k] + w1 * f[1][k] + w2 * f[2][k] +
                      w3 * f[3][k] + w4 * f[4][k] + w5 * f[5][k];
            mx = fmaxf(mx, y);
        }
        qb[(size_t)o * NPTS] = mx;
    }

    // ---- stats: wave 0 only (64-query wave sums, double atomics) ----
    if (wvu == 0) {
        float s1[CIN];
#pragma unroll
        for (int c = 0; c < CIN; c++) {
            float s = 0.f;
#pragma unroll
            for (int k = 0; k < K_NN; k++) s += f[c][k];
            s1[c] = s;
        }
        float s2[21];
#pragma unroll
        for (int i = 0; i < 21; i++) s2[i] = 0.f;
#pragma unroll
        for (int k = 0; k < K_NN; k++) {
            int pp = 0;
#pragma unroll
            for (int c = 0; c < CIN; c++)
#pragma unroll
                for (int c2 = c; c2 < CIN; c2++) {
                    s2[pp] += f[c][k] * f[c2][k];
                    pp++;
                }
        }
#pragma unroll
        for (int c = 0; c < CIN; c++) s1[c] = wave_sum(s1[c]);
#pragma unroll
        for (int i = 0; i < 21; i++) s2[i] = wave_sum(s2[i]);

        if (ln == 0) {
#pragma unroll
            for (int c = 0; c < CIN; c++) sstat[c] = s1[c];
#pragma unroll
            for (int i = 0; i < 21; i++) sstat[6 + i] = s2[i];
        }
        // same-wave LDS write->read ordered by lgkmcnt (no barrier needed)
        if (ln < 27) atomicAdd(&stats[ln], (double)sstat[ln]);
    }
}

// ---- Kernel C: fold moments -> scale/shift (in-block); leaky; reduce max+mean ----
__global__ __launch_bounds__(256) void reduce_kernel(const float* __restrict__ q,
                                                     const double* __restrict__ stats,
                                                     const float* __restrict__ W,
                                                     const float* __restrict__ gamma,
                                                     const float* __restrict__ beta,
                                                     float* __restrict__ out) {
    int o = blockIdx.x;
    int b = blockIdx.y;

    __shared__ float s_sc, s_sh;
    if (threadIdx.x == 0) {
        const double minv = 1.0 / (double)((size_t)BATCH * NPTS * K_NN);
        double w[CIN];
#pragma unroll
        for (int c = 0; c < CIN; c++) w[c] = (double)W[o * CIN + c];
        double mu = 0.0;
#pragma unroll
        for (int c = 0; c < CIN; c++) mu += w[c] * stats[c];
        mu *= minv;
        double ey2 = 0.0;
        int pp = 6;
#pragma unroll
        for (int c = 0; c < CIN; c++)
#pragma unroll
            for (int c2 = c; c2 < CIN; c2++) {
                double v = w[c] * w[c2] * stats[pp];
                ey2 += (c2 == c) ? v : 2.0 * v;
                pp++;
            }
        ey2 *= minv;
        double var = ey2 - mu * mu;
        float scale = gamma[o] * rsqrtf((float)var + BN_EPS);
        float shift = beta[o] - (float)mu * scale;
        s_sc = scale;
        s_sh = shift;
    }
    __syncthreads();
    float scale = s_sc, shift = s_sh;

    const float* qp = q + ((size_t)b * COUT + o) * NPTS;
    float mx = -FLT_MAX, sm = 0.f;
    for (int i = threadIdx.x; i < NPTS; i += 256) {
        float z = scale * qp[i] + shift;
        z = (z >= 0.f) ? z : NEG_SLOPE * z;
        mx = fmaxf(mx, z);
        sm += z;
    }
    mx = wave_max(mx);
    sm = wave_sum(sm);
    __shared__ float smx[4], ssm2[4];
    int wv = threadIdx.x >> 6;
    int ln = threadIdx.x & 63;
    if (ln == 0) { smx[wv] = mx; ssm2[wv] = sm; }
    __syncthreads();
    if (threadIdx.x == 0) {
        float m = fmaxf(fmaxf(smx[0], smx[1]), fmaxf(smx[2], smx[3]));
        float s = ssm2[0] + ssm2[1] + ssm2[2] + ssm2[3];
        out[b * 2 * COUT + o] = m;
        out[b * 2 * COUT + COUT + o] = s * (1.0f / (float)NPTS);
    }
}

extern "C" void kernel_launch(void* const* d_in, const int* in_sizes, int n_in,
                              void* d_out, int out_size, void* d_ws, size_t ws_size,
                              hipStream_t stream) {
    const float* x     = (const float*)d_in[0];
    const float* W     = (const float*)d_in[1];
    const float* gamma = (const float*)d_in[2];
    const float* beta  = (const float*)d_in[3];
    float* out = (float*)d_out;

    char* ws = (char*)d_ws;
    float4* pts   = (float4*)(ws + OFF_PTS);
    float4* pts2  = (float4*)(ws + OFF_PTS2);
    float4* ptsp  = (float4*)(ws + OFF_PTSP);
    float*  q     = (float*)(ws + OFF_Q);
    double* stats = (double*)(ws + OFF_ST);

    prep_pts<<<BATCH * NPTS / 256, 256, 0, stream>>>(x, pts, pts2, ptsp, stats);
    knnmf_kernel<<<dim3(NPTS / 64, BATCH), 512, 0, stream>>>(pts, pts2, ptsp, W, q, stats);
    reduce_kernel<<<dim3(COUT, BATCH), 256, 0, stream>>>(q, stats, W, gamma, beta, out);
}

// Round 11
// 163.696 us; speedup vs baseline: 1.1855x; 1.0003x over previous
//
#include <hip/hip_runtime.h>
#include <float.h>

#define K_NN 10
#define BATCH 8
#define CIN 6
#define NPTS 4096
#define COUT 64
#define NSEG 8
#define SEGLEN (NPTS / NSEG)    // 512
#define CHUNK 16
#define NCHUNK (SEGLEN / CHUNK) // 32
#define NWORD (SEGLEN / 32)     // 16
#define NEG_SLOPE 0.2f
#define BN_EPS 1e-5f

// ---- workspace layout (bytes) ----
static constexpr size_t OFF_PTS  = 0;                                                    // float4[8*4096] (2x,2y,2z,|p|^2)
static constexpr size_t OFF_PTS2 = OFF_PTS + (size_t)BATCH * NPTS * sizeof(float4);      // float4[8*4096] (x3,x4,x5,0)
static constexpr size_t OFF_PTSP = OFF_PTS2 + (size_t)BATCH * NPTS * sizeof(float4);     // float4[8*4096] pair-interleaved
static constexpr size_t OFF_Q    = OFF_PTSP + (size_t)BATCH * NPTS * sizeof(float4);     // float[8*64*4096]
static constexpr size_t OFF_ST   = OFF_Q + (size_t)BATCH * COUT * NPTS * sizeof(float);  // double[27]

typedef float v2f __attribute__((ext_vector_type(2)));

__device__ __forceinline__ float wave_sum(float v) {
#pragma unroll
    for (int m = 32; m >= 1; m >>= 1) v += __shfl_xor(v, m, 64);
    return v;
}
__device__ __forceinline__ float wave_max(float v) {
#pragma unroll
    for (int m = 32; m >= 1; m >>= 1) v = fmaxf(v, __shfl_xor(v, m, 64));
    return v;
}

// pts stores (2x, 2y, 2z, ||p||^2); query coords pre-halved once per thread.
// d' = 2*inner - ||c||^2 -> 3 FMAs. Monotone shift of true distance, used
// consistently in knn/drain/merge. DO NOT reorder (bit-stable).
__device__ __forceinline__ float distp(float qx, float qy, float qz, float4 c) {
    return fmaf(c.x, qx, fmaf(c.y, qy, fmaf(c.z, qz, -c.w)));
}

// Packed pair distance: fa=(x0,x1,y0,y1), fb=(z0,z1,w0,w1) (pre-doubled xyz).
// Identical fma chain per element as distp -> BIT-IDENTICAL (r7/r10-verified,
// absmax 0.0); lowers to v_pk_fma_f32 on gfx950.
__device__ __forceinline__ v2f dist2(v2f qx2, v2f qy2, v2f qz2, float4 fa, float4 fb) {
    v2f cx = {fa.x, fa.y}, cy = {fa.z, fa.w}, cz = {fb.x, fb.y}, cw = {fb.z, fb.w};
#if __has_builtin(__builtin_elementwise_fma)
    v2f t = __builtin_elementwise_fma(cz, qz2, -cw);
    t = __builtin_elementwise_fma(cy, qy2, t);
    t = __builtin_elementwise_fma(cx, qx2, t);
    return t;
#else
    v2f t;
    t[0] = fmaf(cx[0], qx2[0], fmaf(cy[0], qy2[0], fmaf(cz[0], qz2[0], -cw[0])));
    t[1] = fmaf(cx[1], qx2[1], fmaf(cy[1], qy2[1], fmaf(cz[1], qz2[1], -cw[1])));
    return t;
#endif
}

__device__ __forceinline__ v2f vmax2(v2f a, v2f b) {
#if __has_builtin(__builtin_elementwise_max)
    return __builtin_elementwise_max(a, b);   // v_pk_max_f32
#else
    v2f r; r[0] = fmaxf(a[0], b[0]); r[1] = fmaxf(a[1], b[1]); return r;
#endif
}

// 10-deep chunk-max chain level
#define CHL(cj) { float _hi = fmaxf(cj, t); t = fminf(cj, t); cj = _hi; }

// one conditional swap level of the insertion sort
#define CSWP(va, vb, ia, ib) \
    if (va > vb) { float _tv = va; va = vb; vb = _tv; int _ti = ia; ia = ib; ib = _ti; }

// exact strict-> insertion of (d,m) into descending list v0..v9 / i0..i9
#define INSERT10(dd, mm) \
    if ((dd) > v9) { \
        v9 = (dd); i9 = (mm); \
        CSWP(v9, v8, i9, i8) \
        CSWP(v8, v7, i8, i7) \
        CSWP(v7, v6, i7, i6) \
        CSWP(v6, v5, i6, i5) \
        CSWP(v5, v4, i5, i4) \
        CSWP(v4, v3, i4, i3) \
        CSWP(v3, v2, i3, i2) \
        CSWP(v2, v1, i2, i1) \
        CSWP(v1, v0, i1, i0) \
    }

// ---- Kernel P: pack pts / pts2 / ptsp (pair-interleaved); zero stats ----
__global__ __launch_bounds__(256) void prep_pts(const float* __restrict__ x,
                                                float4* __restrict__ pts,
                                                float4* __restrict__ pts2,
                                                float4* __restrict__ ptsp,
                                                double* __restrict__ stats) {
    if (blockIdx.x == 0 && threadIdx.x < 27) stats[threadIdx.x] = 0.0;
    int t = blockIdx.x * 256 + threadIdx.x;   // 0..32767
    int b = t >> 12;
    int n = t & (NPTS - 1);
    const float* xb = x + (size_t)b * CIN * NPTS;
    float X = xb[n];
    float Y = xb[NPTS + n];
    float Z = xb[2 * NPTS + n];
    float w = X * X + Y * Y + Z * Z;
    pts[t] = make_float4(2.0f * X, 2.0f * Y, 2.0f * Z, w);
    float x3 = xb[3 * NPTS + n];
    float x4 = xb[4 * NPTS + n];
    float x5 = xb[5 * NPTS + n];
    pts2[t] = make_float4(x3, x4, x5, 0.0f);
    // neighbor (n+1) via shuffle; even lanes write the pair record (n parity
    // == lane parity: shfl_down(1) valid). r7-verified.
    float Xn = __shfl_down(X, 1, 64);
    float Yn = __shfl_down(Y, 1, 64);
    float Zn = __shfl_down(Z, 1, 64);
    float wn = __shfl_down(w, 1, 64);
    if ((n & 1) == 0) {
        float4* pb = ptsp + (size_t)b * NPTS;
        pb[n]     = make_float4(2.0f * X, 2.0f * Xn, 2.0f * Y, 2.0f * Yn);
        pb[n + 1] = make_float4(2.0f * Z, 2.0f * Zn, w, wn);
    }
}

// ---- Kernel A: FUSED knn + merge + feat (LDS-staged candidates) ----
// Block = 8 waves x 64 queries.  Grid (NPTS/64, BATCH) = 512 blocks.
// ROUND-11: candidate passes read from LDS instead of the scalar path.
//   Every ~79us phase-A variant (r1-r10) shared one element: s_load streaming
//   of 8KB/wave-task through the per-CU K$ (thrashes at 16 tasks/CU -> L2
//   latency on a shallow-MSHR scalar pipe). r7/r10 proved VALU isn't the
//   limit. Fix: wave w stages its segment (pair format, 8KB) into its own
//   LDS slice via the VECTOR path once; both passes then ds_read with wave-
//   uniform addresses (= broadcast, conflict-free per m136).
// After the drain, the slice is dead -> the per-wave top-10 publish ALIASES
// into the slice head (3.75KB), keeping LDS at ~68.5KB -> 2 blocks/CU.
// Distances bit-identical (same dist2 on same data); selection/merge/feat
// arithmetic unchanged from r10 (absmax 0.0).
__global__ __launch_bounds__(512, 4) void knnmf_kernel(const float4* __restrict__ pts,
                                                       const float4* __restrict__ pts2,
                                                       const float4* __restrict__ ptsp,
                                                       const float* __restrict__ W,
                                                       float* __restrict__ q,
                                                       double* __restrict__ stats) {
    __shared__ alignas(16) char smem[NSEG * SEGLEN * sizeof(float4)];  // 64 KB slices
    __shared__ unsigned short idxL[K_NN][64];        // 1.25 KB
    __shared__ float sW[COUT * CIN];                 // 1.5 KB
    __shared__ float sstat[27];

    for (int i = threadIdx.x; i < COUT * CIN; i += 512) sW[i] = W[i];

    int b  = blockIdx.y;
    int ln = threadIdx.x & 63;
    int wv = threadIdx.x >> 6;
    int wvu = __builtin_amdgcn_readfirstlane(wv);   // uniform (round-2 lesson)
    int n  = blockIdx.x * 64 + ln;
    const float4* p   = pts  + (size_t)b * NPTS;
    const float4* p2s = ptsp + (size_t)b * NPTS;
    float4 q4 = p[n];
    float qx = 0.5f * q4.x, qy = 0.5f * q4.y, qz = 0.5f * q4.z;
    v2f qx2 = {qx, qx}, qy2 = {qy, qy}, qz2 = {qz, qz};
    int m0 = wvu * SEGLEN;                          // UNIFORM segment base

    float4* slice = (float4*)(smem + (size_t)wvu * (SEGLEN * sizeof(float4)));

    // ---- stage segment wvu (pair format) into this wave's slice ----
    // Coalesced vector loads (1KB/inst/wave); no barrier needed: same-wave
    // ds_write -> ds_read ordered by lgkmcnt.
    {
        const float4* src = p2s + m0;
#pragma unroll
        for (int i = 0; i < SEGLEN / 64; i++)
            slice[ln + 64 * i] = src[ln + 64 * i];
    }

    // ================= Phase A: knn body, segment wvu (LDS reads) ===========
    {
        // ---- pass 1: threshold from chunk maxima (packed, 8 pairs/chunk) ----
        float c0 = -FLT_MAX, c1 = -FLT_MAX, c2 = -FLT_MAX, c3 = -FLT_MAX, c4 = -FLT_MAX;
        float c5 = -FLT_MAX, c6 = -FLT_MAX, c7 = -FLT_MAX, c8 = -FLT_MAX, c9 = -FLT_MAX;

        for (int ch = 0; ch < NCHUNK; ch++) {
            const float4* cp = slice + ch * CHUNK;   // 16 float4 = 8 pairs (LDS)
            v2f e0 = dist2(qx2, qy2, qz2, cp[0],  cp[1]);
            v2f e1 = dist2(qx2, qy2, qz2, cp[2],  cp[3]);
            v2f e2 = dist2(qx2, qy2, qz2, cp[4],  cp[5]);
            v2f e3 = dist2(qx2, qy2, qz2, cp[6],  cp[7]);
            v2f e4 = dist2(qx2, qy2, qz2, cp[8],  cp[9]);
            v2f e5 = dist2(qx2, qy2, qz2, cp[10], cp[11]);
            v2f e6 = dist2(qx2, qy2, qz2, cp[12], cp[13]);
            v2f e7 = dist2(qx2, qy2, qz2, cp[14], cp[15]);
            v2f a0 = vmax2(e0, e1);
            v2f a1 = vmax2(e2, e3);
            v2f a2 = vmax2(e4, e5);
            v2f a3 = vmax2(e6, e7);
            v2f b0 = vmax2(a0, a1);
            v2f b1 = vmax2(a2, a3);
            v2f cm = vmax2(b0, b1);
            float t = fmaxf(cm[0], cm[1]);        // exact: max reorder-invariant
            CHL(c0) CHL(c1) CHL(c2) CHL(c3) CHL(c4)
            CHL(c5) CHL(c6) CHL(c7) CHL(c8) CHL(c9)
        }
        float thr = c9;   // 10th-largest chunk max (<= exact v10) -- same value as r10

        // ---- pass 2 + drain: bitmask survivors (packed, LDS), exact insert ----
        float v0 = -FLT_MAX, v1 = -FLT_MAX, v2 = -FLT_MAX, v3 = -FLT_MAX, v4 = -FLT_MAX;
        float v5 = -FLT_MAX, v6 = -FLT_MAX, v7 = -FLT_MAX, v8 = -FLT_MAX, v9 = -FLT_MAX;
        int i0 = 0, i1 = 0, i2 = 0, i3 = 0, i4 = 0;
        int i5 = 0, i6 = 0, i7 = 0, i8 = 0, i9 = 0;

        for (int w = 0; w < NWORD; w++) {
            const float4* cp = slice + w * 32;    // 32 pts = 16 pairs (LDS)
            unsigned int mask = 0u;
#pragma unroll
            for (int pr = 0; pr < 16; pr++) {
                v2f d2v = dist2(qx2, qy2, qz2, cp[2 * pr], cp[2 * pr + 1]);
                // point 2pr -> higher bit, 2pr+1 -> lower: bit(31-u) = point u
                mask = (mask << 2) | (d2v[0] >= thr ? 2u : 0u) | (d2v[1] >= thr ? 1u : 0u);
            }
            int base = m0 + w * 32;
            while (mask) {
                int j = __builtin_clz(mask);        // MSB-first == ascending m
                mask ^= (0x80000000u >> j);
                int m = base + j;
                float4 cc = p[m];                   // divergent global, L1-hot
                float d = distp(qx, qy, qz, cc);
                INSERT10(d, m)
            }
        }

        // ---- publish into OWN slice head (slice is dead after drain) ----
        float* dpub = (float*)slice;                               // [10][64] f32
        unsigned short* ipub = (unsigned short*)((char*)slice + K_NN * 64 * sizeof(float));
        dpub[0 * 64 + ln] = v0; ipub[0 * 64 + ln] = (unsigned short)i0;
        dpub[1 * 64 + ln] = v1; ipub[1 * 64 + ln] = (unsigned short)i1;
        dpub[2 * 64 + ln] = v2; ipub[2 * 64 + ln] = (unsigned short)i2;
        dpub[3 * 64 + ln] = v3; ipub[3 * 64 + ln] = (unsigned short)i3;
        dpub[4 * 64 + ln] = v4; ipub[4 * 64 + ln] = (unsigned short)i4;
        dpub[5 * 64 + ln] = v5; ipub[5 * 64 + ln] = (unsigned short)i5;
        dpub[6 * 64 + ln] = v6; ipub[6 * 64 + ln] = (unsigned short)i6;
        dpub[7 * 64 + ln] = v7; ipub[7 * 64 + ln] = (unsigned short)i7;
        dpub[8 * 64 + ln] = v8; ipub[8 * 64 + ln] = (unsigned short)i8;
        dpub[9 * 64 + ln] = v9; ipub[9 * 64 + ln] = (unsigned short)i9;
    }
    __syncthreads();

    // ---- Phase B: wave 0 merges 8x10 -> idxL (s asc, j asc order) ----
    if (wvu == 0) {
        float v0 = -FLT_MAX, v1 = -FLT_MAX, v2 = -FLT_MAX, v3 = -FLT_MAX, v4 = -FLT_MAX;
        float v5 = -FLT_MAX, v6 = -FLT_MAX, v7 = -FLT_MAX, v8 = -FLT_MAX, v9 = -FLT_MAX;
        int i0 = 0, i1 = 0, i2 = 0, i3 = 0, i4 = 0;
        int i5 = 0, i6 = 0, i7 = 0, i8 = 0, i9 = 0;
#pragma unroll
        for (int w = 0; w < NSEG; w++) {
            const float* dp = (const float*)(smem + (size_t)w * (SEGLEN * sizeof(float4)));
            const unsigned short* ip = (const unsigned short*)((const char*)dp + K_NN * 64 * sizeof(float));
#pragma unroll
            for (int j = 0; j < K_NN; j++) {
                float d = dp[j * 64 + ln];
                int m = ip[j * 64 + ln];
                INSERT10(d, m)
            }
        }
        idxL[0][ln] = (unsigned short)i0;
        idxL[1][ln] = (unsigned short)i1;
        idxL[2][ln] = (unsigned short)i2;
        idxL[3][ln] = (unsigned short)i3;
        idxL[4][ln] = (unsigned short)i4;
        idxL[5][ln] = (unsigned short)i5;
        idxL[6][ln] = (unsigned short)i6;
        idxL[7][ln] = (unsigned short)i7;
        idxL[8][ln] = (unsigned short)i8;
        idxL[9][ln] = (unsigned short)i9;
    }
    __syncthreads();

    // ================= Phase C: feat (wave w -> channels [8w, 8w+8)) ========
    const float4* p2 = pts2 + (size_t)b * NPTS;

    int nb[K_NN];
#pragma unroll
    for (int k = 0; k < K_NN; k++) nb[k] = idxL[k][ln];

    float f[CIN][K_NN];
#pragma unroll
    for (int k = 0; k < K_NN; k++) {
        float4 c = p[nb[k]];                    // xyz in one 16B gather (doubled)
        f[0][k] = 0.5f * c.x; f[1][k] = 0.5f * c.y; f[2][k] = 0.5f * c.z;
    }
#pragma unroll
    for (int k = 0; k < K_NN; k++) {
        float4 c2 = p2[nb[k]];                  // ch 3-5 in one 16B gather
        f[3][k] = c2.x; f[4][k] = c2.y; f[5][k] = c2.z;
    }

    // center xyz over k, scale by 10
#pragma unroll
    for (int c = 0; c < 3; c++) {
        float s = 0.f;
#pragma unroll
        for (int k = 0; k < K_NN; k++) s += f[c][k];
        float m = s / 10.0f;
#pragma unroll
        for (int k = 0; k < K_NN; k++) f[c][k] = (f[c][k] - m) * 10.0f;
    }

    // q[b,o,n] = max_k y, 8 channels per wave (same per-(o,n) op order)
    float* qb = q + (size_t)b * COUT * NPTS + n;
    int o0 = wvu * 8;
#pragma unroll
    for (int oo = 0; oo < 8; oo++) {
        int o = o0 + oo;
        float w0 = sW[o * 6 + 0], w1 = sW[o * 6 + 1], w2 = sW[o * 6 + 2];
        float w3 = sW[o * 6 + 3], w4 = sW[o * 6 + 4], w5 = sW[o * 6 + 5];
        float mx = -FLT_MAX;
#pragma unroll
        for (int k = 0; k < K_NN; k++) {
            float y = w0 * f[0][k] + w1 * f[1][k] + w2 * f[2][k] +
                      w3 * f[3][k] + w4 * f[4][k] + w5 * f[5][k];
            mx = fmaxf(mx, y);
        }
        qb[(size_t)o * NPTS] = mx;
    }

    // ---- stats: wave 0 only (64-query wave sums, double atomics) ----
    if (wvu == 0) {
        float s1[CIN];
#pragma unroll
        for (int c = 0; c < CIN; c++) {
            float s = 0.f;
#pragma unroll
            for (int k = 0; k < K_NN; k++) s += f[c][k];
            s1[c] = s;
        }
        float s2[21];
#pragma unroll
        for (int i = 0; i < 21; i++) s2[i] = 0.f;
#pragma unroll
        for (int k = 0; k < K_NN; k++) {
            int pp = 0;
#pragma unroll
            for (int c = 0; c < CIN; c++)
#pragma unroll
                for (int c2 = c; c2 < CIN; c2++) {
                    s2[pp] += f[c][k] * f[c2][k];
                    pp++;
                }
        }
#pragma unroll
        for (int c = 0; c < CIN; c++) s1[c] = wave_sum(s1[c]);
#pragma unroll
        for (int i = 0; i < 21; i++) s2[i] = wave_sum(s2[i]);

        if (ln == 0) {
#pragma unroll
            for (int c = 0; c < CIN; c++) sstat[c] = s1[c];
#pragma unroll
            for (int i = 0; i < 21; i++) sstat[6 + i] = s2[i];
        }
        // same-wave LDS write->read ordered by lgkmcnt (no barrier needed)
        if (ln < 27) atomicAdd(&stats[ln], (double)sstat[ln]);
    }
}

// ---- Kernel C: fold moments -> scale/shift (in-block); leaky; reduce max+mean ----
__global__ __launch_bounds__(256) void reduce_kernel(const float* __restrict__ q,
                                                     const double* __restrict__ stats,
                                                     const float* __restrict__ W,
                                                     const float* __restrict__ gamma,
                                                     const float* __restrict__ beta,
                                                     float* __restrict__ out) {
    int o = blockIdx.x;
    int b = blockIdx.y;

    __shared__ float s_sc, s_sh;
    if (threadIdx.x == 0) {
        const double minv = 1.0 / (double)((size_t)BATCH * NPTS * K_NN);
        double w[CIN];
#pragma unroll
        for (int c = 0; c < CIN; c++) w[c] = (double)W[o * CIN + c];
        double mu = 0.0;
#pragma unroll
        for (int c = 0; c < CIN; c++) mu += w[c] * stats[c];
        mu *= minv;
        double ey2 = 0.0;
        int pp = 6;
#pragma unroll
        for (int c = 0; c < CIN; c++)
#pragma unroll
            for (int c2 = c; c2 < CIN; c2++) {
                double v = w[c] * w[c2] * stats[pp];
                ey2 += (c2 == c) ? v : 2.0 * v;
                pp++;
            }
        ey2 *= minv;
        double var = ey2 - mu * mu;
        float scale = gamma[o] * rsqrtf((float)var + BN_EPS);
        float shift = beta[o] - (float)mu * scale;
        s_sc = scale;
        s_sh = shift;
    }
    __syncthreads();
    float scale = s_sc, shift = s_sh;

    const float* qp = q + ((size_t)b * COUT + o) * NPTS;
    float mx = -FLT_MAX, sm = 0.f;
    for (int i = threadIdx.x; i < NPTS; i += 256) {
        float z = scale * qp[i] + shift;
        z = (z >= 0.f) ? z : NEG_SLOPE * z;
        mx = fmaxf(mx, z);
        sm += z;
    }
    mx = wave_max(mx);
    sm = wave_sum(sm);
    __shared__ float smx[4], ssm2[4];
    int wv = threadIdx.x >> 6;
    int ln = threadIdx.x & 63;
    if (ln == 0) { smx[wv] = mx; ssm2[wv] = sm; }
    __syncthreads();
    if (threadIdx.x == 0) {
        float m = fmaxf(fmaxf(smx[0], smx[1]), fmaxf(smx[2], smx[3]));
        float s = ssm2[0] + ssm2[1] + ssm2[2] + ssm2[3];
        out[b * 2 * COUT + o] = m;
        out[b * 2 * COUT + COUT + o] = s * (1.0f / (float)NPTS);
    }
}

extern "C" void kernel_launch(void* const* d_in, const int* in_sizes, int n_in,
                              void* d_out, int out_size, void* d_ws, size_t ws_size,
                              hipStream_t stream) {
    const float* x     = (const float*)d_in[0];
    const float* W     = (const float*)d_in[1];
    const float* gamma = (const float*)d_in[2];
    const float* beta  = (const float*)d_in[3];
    float* out = (float*)d_out;

    char* ws = (char*)d_ws;
    float4* pts   = (float4*)(ws + OFF_PTS);
    float4* pts2  = (float4*)(ws + OFF_PTS2);
    float4* ptsp  = (float4*)(ws + OFF_PTSP);
    float*  q     = (float*)(ws + OFF_Q);
    double* stats = (double*)(ws + OFF_ST);

    prep_pts<<<BATCH * NPTS / 256, 256, 0, stream>>>(x, pts, pts2, ptsp, stats);
    knnmf_kernel<<<dim3(NPTS / 64, BATCH), 512, 0, stream>>>(pts, pts2, ptsp, W, q, stats);
    reduce_kernel<<<dim3(COUT, BATCH), 256, 0, stream>>>(q, stats, W, gamma, beta, out);
}